// Round 1
// baseline (2263.295 us; speedup 1.0000x reference)
//
#include <hip/hip_runtime.h>
#include <hip/hip_bf16.h>
#include <math.h>

// Problem constants (HashMemory): B=8, S=4096, E=1024, Dm=512, M=64 slots.
// Key identity: memory at step t == write_vals of tokens [max(0,t-64), t-1].
// => sliding-window attention, window 64. No sequential scan needed.

#define BATCH   8
#define S_LEN   4096
#define EMB     1024
#define DM      512
#define MROWS   (BATCH * S_LEN)          // 32768
#define SCALE_F 0.04419417382415922f     // 512^-0.5

// ---------------------------------------------------------------------------
// Generic f32 GEMM: C[M x N] = A[M x K] @ B[K x N] + bias[N]
// 64x64 tile, BK=16, 256 threads, 4x4 micro-tile per thread.
// ---------------------------------------------------------------------------
__global__ __launch_bounds__(256) void gemm64_f32(
    const float* __restrict__ A, int K,
    const float* __restrict__ B, int N,
    const float* __restrict__ bias,
    float* __restrict__ C)
{
    __shared__ float As[16][66];   // +2 pad: store/read bank-friendly
    __shared__ float Bs[16][64];

    const int bn0 = blockIdx.x * 64;
    const int bm0 = blockIdx.y * 64;
    const int tid = threadIdx.x;
    const int tx = tid & 15;       // col group
    const int ty = tid >> 4;       // row group
    const int ar = tid >> 2;               // 0..63  (A tile row)
    const int ak = (tid & 3) << 2;         // 0,4,8,12 (A tile k)
    const int br = tid >> 4;               // 0..15  (B tile k-row)
    const int bc = (tid & 15) << 2;        // 0..60  (B tile col)

    float acc[4][4] = {};

    for (int kt = 0; kt < K; kt += 16) {
        float4 av = *(const float4*)(A + (size_t)(bm0 + ar) * K + kt + ak);
        float4 bv = *(const float4*)(B + (size_t)(kt + br) * N + bn0 + bc);
        As[ak + 0][ar] = av.x;
        As[ak + 1][ar] = av.y;
        As[ak + 2][ar] = av.z;
        As[ak + 3][ar] = av.w;
        *(float4*)&Bs[br][bc] = bv;
        __syncthreads();
#pragma unroll
        for (int k = 0; k < 16; ++k) {
            float4 bq = *(const float4*)&Bs[k][tx * 4];
#pragma unroll
            for (int i = 0; i < 4; ++i) {
                float a = As[k][ty * 4 + i];
                acc[i][0] += a * bq.x;
                acc[i][1] += a * bq.y;
                acc[i][2] += a * bq.z;
                acc[i][3] += a * bq.w;
            }
        }
        __syncthreads();
    }

    float4 bsv = *(const float4*)(bias + bn0 + tx * 4);
#pragma unroll
    for (int i = 0; i < 4; ++i) {
        float4 o;
        o.x = acc[i][0] + bsv.x;
        o.y = acc[i][1] + bsv.y;
        o.z = acc[i][2] + bsv.z;
        o.w = acc[i][3] + bsv.w;
        *(float4*)(C + (size_t)(bm0 + ty * 4 + i) * N + bn0 + tx * 4) = o;
    }
}

// ---------------------------------------------------------------------------
// Sliding-window attention: one wave (64 lanes) per (b, t).
// Lane j owns window slot j: sim_j = Q[b,t] . WV[b, t-cnt+j] * SCALE.
// Shuffle softmax across 64 lanes, then coalesced weighted sum.
// ---------------------------------------------------------------------------
__global__ __launch_bounds__(64) void attn_window64(
    const float* __restrict__ Q,    // [B*S, DM]
    const float* __restrict__ WV,   // [B*S, DM]
    float* __restrict__ R)          // [B*S, DM]
{
    const int bs = blockIdx.x;           // 0 .. B*S-1
    const int t  = bs & (S_LEN - 1);
    const int lane = threadIdx.x;
    const int cnt = t < 64 ? t : 64;

    const float* q = Q + (size_t)bs * DM;

    float sim = -1e30f;
    if (lane < cnt) {
        const float* row = WV + (size_t)(bs - cnt + lane) * DM;
        float a = 0.f;
#pragma unroll 4
        for (int d = 0; d < DM; d += 4) {
            float4 qv = *(const float4*)(q + d);
            float4 rv = *(const float4*)(row + d);
            a += qv.x * rv.x + qv.y * rv.y + qv.z * rv.z + qv.w * rv.w;
        }
        sim = a * SCALE_F;
    }

    // wave max
    float m = sim;
#pragma unroll
    for (int off = 32; off >= 1; off >>= 1)
        m = fmaxf(m, __shfl_xor(m, off, 64));

    float p = (lane < cnt) ? expf(sim - m) : 0.f;

    float s = p;
#pragma unroll
    for (int off = 32; off >= 1; off >>= 1)
        s += __shfl_xor(s, off, 64);

    const float attn = (cnt > 0) ? (p / s) : 0.f;

    // weighted sum: lane handles dims {lane + 64*i}, coalesced across wave
    float acc[8] = {};
    for (int j = 0; j < cnt; ++j) {
        float a = __shfl(attn, j, 64);
        const float* row = WV + (size_t)(bs - cnt + j) * DM;
#pragma unroll
        for (int i = 0; i < 8; ++i)
            acc[i] += a * row[lane + i * 64];
    }

    float* r = R + (size_t)bs * DM;
#pragma unroll
    for (int i = 0; i < 8; ++i)
        r[lane + i * 64] = acc[i];
}

// ---------------------------------------------------------------------------
extern "C" void kernel_launch(void* const* d_in, const int* in_sizes, int n_in,
                              void* d_out, int out_size, void* d_ws, size_t ws_size,
                              hipStream_t stream)
{
    const float* emb    = (const float*)d_in[0];  // [8,4096,1024]
    const float* W_wr   = (const float*)d_in[1];  // [1024,512]
    const float* b_wr   = (const float*)d_in[2];  // [512]
    const float* W_qr   = (const float*)d_in[3];  // [1024,512]
    const float* b_qr   = (const float*)d_in[4];  // [512]
    const float* W_out  = (const float*)d_in[5];  // [512,1024]
    const float* b_out  = (const float*)d_in[6];  // [1024]
    float* out = (float*)d_out;                   // [8,4096,1024]

    // workspace: WV | Q | R, each [32768, 512] f32 = 64 MiB
    const size_t seg = (size_t)MROWS * DM;        // elements
    float* WV = (float*)d_ws;
    float* Qp = WV + seg;
    float* Rp = Qp + seg;

    dim3 blk(256);

    // WV = emb @ W_write + b_write
    gemm64_f32<<<dim3(DM / 64, MROWS / 64), blk, 0, stream>>>(
        emb, EMB, W_wr, DM, b_wr, WV);
    // Q = emb @ W_query + b_query
    gemm64_f32<<<dim3(DM / 64, MROWS / 64), blk, 0, stream>>>(
        emb, EMB, W_qr, DM, b_qr, Qp);
    // windowed attention
    attn_window64<<<dim3(MROWS), dim3(64), 0, stream>>>(Qp, WV, Rp);
    // out = R @ W_out + b_out
    gemm64_f32<<<dim3(EMB / 64, MROWS / 64), blk, 0, stream>>>(
        Rp, DM, W_out, EMB, b_out, out);
}

// Round 3
// 539.867 us; speedup vs baseline: 4.1923x; 4.1923x over previous
//
#include <hip/hip_runtime.h>
#include <hip/hip_bf16.h>
#include <math.h>

// HashMemory: B=8, S=4096, E=1024, Dm=512, M=64 slots.
// memory at step t == write_vals of tokens [t-64, t-1]  => window-64 attention.
// Pipeline: cast emb->bf16; WVQ = emb @ [W_write|W_query] (bf16 MFMA GEMM);
// windowed attention (LDS-staged, VALU); out = R @ W_out (bf16 MFMA GEMM, f32 out).

#define BATCH   8
#define S_LEN   4096
#define EMB     1024
#define DM      512
#define MROWS   (BATCH * S_LEN)          // 32768
#define SCALE_F 0.04419417382415922f     // 512^-0.5

typedef __attribute__((ext_vector_type(4))) float f32x4;
typedef __attribute__((ext_vector_type(8))) short short8;

__device__ __forceinline__ unsigned short f2bf(float f) {
    __hip_bfloat16 h = __float2bfloat16(f);
    return *reinterpret_cast<unsigned short*>(&h);
}
__device__ __forceinline__ float bflo(unsigned u) { return __uint_as_float(u << 16); }
__device__ __forceinline__ float bfhi(unsigned u) { return __uint_as_float(u & 0xffff0000u); }

// ---------------------------------------------------------------------------
// f32 -> bf16 cast, 4 elems/thread
// ---------------------------------------------------------------------------
__global__ __launch_bounds__(256) void cast_bf16(const float4* __restrict__ in,
                                                 ushort4* __restrict__ out, int n4)
{
    int id = blockIdx.x * 256 + threadIdx.x;
    if (id >= n4) return;
    float4 v = in[id];
    ushort4 o;
    o.x = f2bf(v.x); o.y = f2bf(v.y); o.z = f2bf(v.z); o.w = f2bf(v.w);
    out[id] = o;
}

// transpose + cast: in f32 [K][N] -> out bf16 [N][K]
__global__ __launch_bounds__(256) void tcast(const float* __restrict__ in,
                                             __hip_bfloat16* __restrict__ out,
                                             int K, int N)
{
    int id = blockIdx.x * 256 + threadIdx.x;
    if (id >= K * N) return;
    int n = id / K, k = id % K;
    out[id] = __float2bfloat16(in[k * N + n]);
}

__global__ __launch_bounds__(256) void concat_bias(const float* __restrict__ a,
                                                   const float* __restrict__ b,
                                                   float* __restrict__ out)
{
    int i = blockIdx.x * 256 + threadIdx.x;
    if (i < 512) out[i] = a[i];
    else if (i < 1024) out[i] = b[i - 512];
}

// ---------------------------------------------------------------------------
// bf16 MFMA GEMM: C[M x N] = A[M x K] @ Bt[N x K]^T + bias.
// 128x128 tile, BK=32, 256 threads (4 waves, 2x2 wave grid, 64x64 per wave).
// global_load_lds width-16 staging; XOR granule swizzle (slot ^= (r>>1)&3)
// makes the ds_read_b128 fragment reads bank-conflict-free.
// ---------------------------------------------------------------------------
template<bool BF16OUT>
__global__ __launch_bounds__(256) void gemm_mfma(
    const __hip_bfloat16* __restrict__ A, int lda,
    const __hip_bfloat16* __restrict__ Bt, int ldb,
    const float* __restrict__ bias,
    void* __restrict__ Cv, int ldc,
    int K, int nbx)
{
    __shared__ __align__(16) char smem[16384];   // A: [0,8K) B: [8K,16K)

    const int nwg = gridDim.x;
    const int bid = blockIdx.x;
    const int cpx = nwg >> 3;                    // nwg divisible by 8
    const int swz = (bid & 7) * cpx + (bid >> 3);
    const int bm0 = (swz / nbx) << 7;
    const int bn0 = (swz % nbx) << 7;

    const int tid  = threadIdx.x;
    const int lane = tid & 63;
    const int w    = tid >> 6;
    const int wr   = w >> 1, wc = w & 1;

    f32x4 acc[4][4] = {};

    const int rs = lane >> 2;      // staging row within wave's 16-row group
    const int cs = lane & 3;       // staging granule slot

    for (int kt = 0; kt < K; kt += 32) {
#pragma unroll
        for (int p = 0; p < 2; ++p) {
            int r   = p * 64 + w * 16 + rs;
            int cg  = cs ^ ((r >> 1) & 3);     // inverse-swizzled SOURCE chunk
            const __hip_bfloat16* ga = A  + (size_t)(bm0 + r) * lda + kt + cg * 8;
            const __hip_bfloat16* gb = Bt + (size_t)(bn0 + r) * ldb + kt + cg * 8;
            char* la = smem +        p * 4096 + w * 1024;
            char* lb = smem + 8192 + p * 4096 + w * 1024;
            __builtin_amdgcn_global_load_lds(
                (const __attribute__((address_space(1))) unsigned int*)ga,
                (__attribute__((address_space(3))) unsigned int*)la, 16, 0, 0);
            __builtin_amdgcn_global_load_lds(
                (const __attribute__((address_space(1))) unsigned int*)gb,
                (__attribute__((address_space(3))) unsigned int*)lb, 16, 0, 0);
        }
        __syncthreads();

        short8 af[4], bfr[4];
#pragma unroll
        for (int m = 0; m < 4; ++m) {
            int r = wr * 64 + m * 16 + (lane & 15);
            int slot = (lane >> 4) ^ ((r >> 1) & 3);   // swizzled READ
            af[m] = *(const short8*)(smem + r * 64 + slot * 16);
        }
#pragma unroll
        for (int n = 0; n < 4; ++n) {
            int r = wc * 64 + n * 16 + (lane & 15);
            int slot = (lane >> 4) ^ ((r >> 1) & 3);
            bfr[n] = *(const short8*)(smem + 8192 + r * 64 + slot * 16);
        }
#pragma unroll
        for (int m = 0; m < 4; ++m)
#pragma unroll
            for (int n = 0; n < 4; ++n)
                acc[m][n] = __builtin_amdgcn_mfma_f32_16x16x32_bf16(
                    af[m], bfr[n], acc[m][n], 0, 0, 0);
        __syncthreads();
    }

    float bv[4];
#pragma unroll
    for (int n = 0; n < 4; ++n)
        bv[n] = bias[bn0 + wc * 64 + n * 16 + (lane & 15)];

#pragma unroll
    for (int m = 0; m < 4; ++m)
#pragma unroll
        for (int n = 0; n < 4; ++n)
#pragma unroll
            for (int reg = 0; reg < 4; ++reg) {
                int row = bm0 + wr * 64 + m * 16 + ((lane >> 4) << 2) + reg;
                int col = bn0 + wc * 64 + n * 16 + (lane & 15);
                float v = acc[m][n][reg] + bv[n];
                if (BF16OUT)
                    ((__hip_bfloat16*)Cv)[(size_t)row * ldc + col] = __float2bfloat16(v);
                else
                    ((float*)Cv)[(size_t)row * ldc + col] = v;
            }
}

// ---------------------------------------------------------------------------
// Windowed attention, 16 tokens/block, window rows staged once in LDS (bf16).
// wv row stride 520 bf16 = 65 x 16B (odd granule stride -> conflict-free).
// ---------------------------------------------------------------------------
__global__ __launch_bounds__(256) void attn16(
    const __hip_bfloat16* __restrict__ WVQ,   // [32768][1024]: 0:512=WV, 512:=Q
    __hip_bfloat16* __restrict__ R)           // [32768][512]
{
    __shared__ __align__(16) unsigned short wv[80][520];
    __shared__ __align__(16) unsigned short qs[16][512];

    const int blk = blockIdx.x;
    const int b   = blk >> 8;                  // 256 blocks per batch
    const int t0  = (blk & 255) << 4;
    const size_t base = ((size_t)b << 12) + t0;
    const int tid  = threadIdx.x;
    const int lane = tid & 63;
    const int w    = tid >> 6;

    // stage WV rows [t0-64, t0+16)
    for (int idx = tid; idx < 80 * 64; idx += 256) {
        int r  = idx >> 6;
        int c8 = (idx & 63) << 3;
        if (t0 + r >= 64)   // row exists within this batch
            *(uint4*)&wv[r][c8] =
                *(const uint4*)&WVQ[(base - 64 + r) * 1024 + c8];
    }
    // stage Q rows
    for (int idx = tid; idx < 16 * 64; idx += 256) {
        int r  = idx >> 6;
        int c8 = (idx & 63) << 3;
        *(uint4*)&qs[r][c8] =
            *(const uint4*)&WVQ[(base + r) * 1024 + 512 + c8];
    }
    __syncthreads();

#pragma unroll
    for (int i = 0; i < 4; ++i) {
        int tt  = (w << 2) + i;
        int t   = t0 + tt;
        int cnt = t < 64 ? t : 64;
        int r0  = tt + 64 - cnt;

        float sim = -1e30f;
        if (lane < cnt) {
            const unsigned short* row = &wv[r0 + lane][0];
            const unsigned short* q   = &qs[tt][0];
            float a = 0.f;
#pragma unroll 4
            for (int d = 0; d < 512; d += 8) {
                uint4 rv = *(const uint4*)(row + d);
                uint4 qv = *(const uint4*)(q + d);
                a += bflo(rv.x) * bflo(qv.x) + bfhi(rv.x) * bfhi(qv.x);
                a += bflo(rv.y) * bflo(qv.y) + bfhi(rv.y) * bfhi(qv.y);
                a += bflo(rv.z) * bflo(qv.z) + bfhi(rv.z) * bfhi(qv.z);
                a += bflo(rv.w) * bflo(qv.w) + bfhi(rv.w) * bfhi(qv.w);
            }
            sim = a * SCALE_F;
        }

        float m = sim;
#pragma unroll
        for (int off = 32; off >= 1; off >>= 1)
            m = fmaxf(m, __shfl_xor(m, off, 64));
        float p = (lane < cnt) ? __expf(sim - m) : 0.f;
        float s = p;
#pragma unroll
        for (int off = 32; off >= 1; off >>= 1)
            s += __shfl_xor(s, off, 64);
        float attn = (cnt > 0) ? p / s : 0.f;

        float acc[8] = {};
        for (int j = 0; j < cnt; ++j) {
            float aw = __shfl(attn, j, 64);
            uint4 rv = *(const uint4*)&wv[r0 + j][lane << 3];
            acc[0] += aw * bflo(rv.x);  acc[1] += aw * bfhi(rv.x);
            acc[2] += aw * bflo(rv.y);  acc[3] += aw * bfhi(rv.y);
            acc[4] += aw * bflo(rv.z);  acc[5] += aw * bfhi(rv.z);
            acc[6] += aw * bflo(rv.w);  acc[7] += aw * bfhi(rv.w);
        }

        union { unsigned short s[8]; uint4 v; } o;
#pragma unroll
        for (int k = 0; k < 8; ++k) o.s[k] = f2bf(acc[k]);
        *(uint4*)&R[(base + tt) * 512 + (lane << 3)] = o.v;
    }
}

// ---------------------------------------------------------------------------
extern "C" void kernel_launch(void* const* d_in, const int* in_sizes, int n_in,
                              void* d_out, int out_size, void* d_ws, size_t ws_size,
                              hipStream_t stream)
{
    const float* emb   = (const float*)d_in[0];  // [8,4096,1024]
    const float* W_wr  = (const float*)d_in[1];  // [1024,512]
    const float* b_wr  = (const float*)d_in[2];  // [512]
    const float* W_qr  = (const float*)d_in[3];  // [1024,512]
    const float* b_qr  = (const float*)d_in[4];  // [512]
    const float* W_out = (const float*)d_in[5];  // [512,1024]
    const float* b_out = (const float*)d_in[6];  // [1024]
    float* out = (float*)d_out;                  // [8,4096,1024]

    char* ws = (char*)d_ws;
    __hip_bfloat16* embb = (__hip_bfloat16*)(ws);                         // 64MB
    __hip_bfloat16* wvq  = (__hip_bfloat16*)(ws + (((size_t)64) << 20));  // 64MB
    __hip_bfloat16* rbuf = (__hip_bfloat16*)(ws + (((size_t)128) << 20)); // 32MB
    __hip_bfloat16* wcat = (__hip_bfloat16*)(ws + (((size_t)160) << 20)); // 2MB
    __hip_bfloat16* wout = (__hip_bfloat16*)(ws + (((size_t)162) << 20)); // 1MB
    float*          bcat = (float*)        (ws + (((size_t)163) << 20));  // 4KB

    // 1. casts / transposes
    cast_bf16<<<dim3((MROWS * EMB / 4) / 256), dim3(256), 0, stream>>>(
        (const float4*)emb, (ushort4*)embb, MROWS * EMB / 4);
    tcast<<<dim3(2048), dim3(256), 0, stream>>>(W_wr, wcat, EMB, DM);
    tcast<<<dim3(2048), dim3(256), 0, stream>>>(W_qr, wcat + (size_t)DM * EMB, EMB, DM);
    tcast<<<dim3(2048), dim3(256), 0, stream>>>(W_out, wout, DM, EMB);
    concat_bias<<<dim3(4), dim3(256), 0, stream>>>(b_wr, b_qr, bcat);

    // 2. WVQ = embb @ Wcat^T + bcat   (M=32768, N=1024, K=1024), bf16 out
    gemm_mfma<true><<<dim3(2048), dim3(256), 0, stream>>>(
        embb, EMB, wcat, EMB, bcat, (void*)wvq, 1024, EMB, 8);

    // 3. windowed attention -> R bf16 [32768][512]
    attn16<<<dim3(MROWS / 16), dim3(256), 0, stream>>>(wvq, rbuf);

    // 4. out = R @ W_out^T + b_out    (M=32768, N=1024, K=512), f32 out
    gemm_mfma<false><<<dim3(2048), dim3(256), 0, stream>>>(
        rbuf, DM, wout, DM, b_out, (void*)out, EMB, DM, 8);
}

// Round 4
// 285.528 us; speedup vs baseline: 7.9267x; 1.8908x over previous
//
#include <hip/hip_runtime.h>
#include <hip/hip_bf16.h>
#include <math.h>

// HashMemory: B=8, S=4096, E=1024, Dm=512, M=64 slots.
// memory at step t == write_vals of tokens [t-64, t-1]  => window-64 attention.
// Pipeline: cast emb->bf16; WVQ = emb @ [W_write|W_query] (bf16 MFMA GEMM);
// WVT = WV^T (tiled transpose); windowed attention (MFMA QK^T + wave-local
// softmax + MFMA PV); out = R @ W_out (bf16 MFMA GEMM, f32 out).

#define BATCH   8
#define S_LEN   4096
#define EMB     1024
#define DM      512
#define MROWS   (BATCH * S_LEN)          // 32768
#define SCALE_F 0.04419417382415922f     // 512^-0.5

typedef __attribute__((ext_vector_type(4))) float f32x4;
typedef __attribute__((ext_vector_type(8))) short short8;

__device__ __forceinline__ unsigned short f2bf(float f) {
    __hip_bfloat16 h = __float2bfloat16(f);
    return *reinterpret_cast<unsigned short*>(&h);
}

// ---------------------------------------------------------------------------
__global__ __launch_bounds__(256) void cast_bf16(const float4* __restrict__ in,
                                                 ushort4* __restrict__ out, int n4)
{
    int id = blockIdx.x * 256 + threadIdx.x;
    if (id >= n4) return;
    float4 v = in[id];
    ushort4 o;
    o.x = f2bf(v.x); o.y = f2bf(v.y); o.z = f2bf(v.z); o.w = f2bf(v.w);
    out[id] = o;
}

__global__ __launch_bounds__(256) void tcast(const float* __restrict__ in,
                                             __hip_bfloat16* __restrict__ out,
                                             int K, int N)
{
    int id = blockIdx.x * 256 + threadIdx.x;
    if (id >= K * N) return;
    int n = id / K, k = id % K;
    out[id] = __float2bfloat16(in[k * N + n]);
}

__global__ __launch_bounds__(256) void concat_bias(const float* __restrict__ a,
                                                   const float* __restrict__ b,
                                                   float* __restrict__ out)
{
    int i = blockIdx.x * 256 + threadIdx.x;
    if (i < 512) out[i] = a[i];
    else if (i < 1024) out[i] = b[i - 512];
}

// ---------------------------------------------------------------------------
// bf16 MFMA GEMM: C[M x N] = A[M x K] @ Bt[N x K]^T + bias.  (verified r3)
// ---------------------------------------------------------------------------
template<bool BF16OUT>
__global__ __launch_bounds__(256) void gemm_mfma(
    const __hip_bfloat16* __restrict__ A, int lda,
    const __hip_bfloat16* __restrict__ Bt, int ldb,
    const float* __restrict__ bias,
    void* __restrict__ Cv, int ldc,
    int K, int nbx)
{
    __shared__ __align__(16) char smem[16384];

    const int nwg = gridDim.x;
    const int bid = blockIdx.x;
    const int cpx = nwg >> 3;
    const int swz = (bid & 7) * cpx + (bid >> 3);
    const int bm0 = (swz / nbx) << 7;
    const int bn0 = (swz % nbx) << 7;

    const int tid  = threadIdx.x;
    const int lane = tid & 63;
    const int w    = tid >> 6;
    const int wr   = w >> 1, wc = w & 1;

    f32x4 acc[4][4] = {};

    const int rs = lane >> 2;
    const int cs = lane & 3;

    for (int kt = 0; kt < K; kt += 32) {
#pragma unroll
        for (int p = 0; p < 2; ++p) {
            int r   = p * 64 + w * 16 + rs;
            int cg  = cs ^ ((r >> 1) & 3);
            const __hip_bfloat16* ga = A  + (size_t)(bm0 + r) * lda + kt + cg * 8;
            const __hip_bfloat16* gb = Bt + (size_t)(bn0 + r) * ldb + kt + cg * 8;
            char* la = smem +        p * 4096 + w * 1024;
            char* lb = smem + 8192 + p * 4096 + w * 1024;
            __builtin_amdgcn_global_load_lds(
                (const __attribute__((address_space(1))) unsigned int*)ga,
                (__attribute__((address_space(3))) unsigned int*)la, 16, 0, 0);
            __builtin_amdgcn_global_load_lds(
                (const __attribute__((address_space(1))) unsigned int*)gb,
                (__attribute__((address_space(3))) unsigned int*)lb, 16, 0, 0);
        }
        __syncthreads();

        short8 af[4], bfr[4];
#pragma unroll
        for (int m = 0; m < 4; ++m) {
            int r = wr * 64 + m * 16 + (lane & 15);
            int slot = (lane >> 4) ^ ((r >> 1) & 3);
            af[m] = *(const short8*)(smem + r * 64 + slot * 16);
        }
#pragma unroll
        for (int n = 0; n < 4; ++n) {
            int r = wc * 64 + n * 16 + (lane & 15);
            int slot = (lane >> 4) ^ ((r >> 1) & 3);
            bfr[n] = *(const short8*)(smem + 8192 + r * 64 + slot * 16);
        }
#pragma unroll
        for (int m = 0; m < 4; ++m)
#pragma unroll
            for (int n = 0; n < 4; ++n)
                acc[m][n] = __builtin_amdgcn_mfma_f32_16x16x32_bf16(
                    af[m], bfr[n], acc[m][n], 0, 0, 0);
        __syncthreads();
    }

    float bv[4];
#pragma unroll
    for (int n = 0; n < 4; ++n)
        bv[n] = bias[bn0 + wc * 64 + n * 16 + (lane & 15)];

#pragma unroll
    for (int m = 0; m < 4; ++m)
#pragma unroll
        for (int n = 0; n < 4; ++n)
#pragma unroll
            for (int reg = 0; reg < 4; ++reg) {
                int row = bm0 + wr * 64 + m * 16 + ((lane >> 4) << 2) + reg;
                int col = bn0 + wc * 64 + n * 16 + (lane & 15);
                float v = acc[m][n][reg] + bv[n];
                if (BF16OUT)
                    ((__hip_bfloat16*)Cv)[(size_t)row * ldc + col] = __float2bfloat16(v);
                else
                    ((float*)Cv)[(size_t)row * ldc + col] = v;
            }
}

// ---------------------------------------------------------------------------
// WV transpose: wvq[b][t][0:512] (stride 1024) -> wvt[b][d][t]
// ---------------------------------------------------------------------------
__global__ __launch_bounds__(256) void transpose_wv(
    const unsigned short* __restrict__ wvq,
    unsigned short* __restrict__ wvt)
{
    __shared__ unsigned short tl[64][66];
    const int tx  = blockIdx.x;
    const int dx  = blockIdx.y;
    const int b   = blockIdx.z;
    const int tid = threadIdx.x;
    const int r   = tid >> 3;
    const int c8  = (tid & 7) * 8;
    const size_t bbase = (size_t)b << 12;

#pragma unroll
    for (int it = 0; it < 2; ++it) {
        int row = r + it * 32;
        uint4 v = *(const uint4*)(wvq + ((bbase + tx * 64 + row) << 10) + dx * 64 + c8);
        *(unsigned*)&tl[row][c8 + 0] = v.x;
        *(unsigned*)&tl[row][c8 + 2] = v.y;
        *(unsigned*)&tl[row][c8 + 4] = v.z;
        *(unsigned*)&tl[row][c8 + 6] = v.w;
    }
    __syncthreads();
#pragma unroll
    for (int it = 0; it < 2; ++it) {
        int drow = r + it * 32;
        union { unsigned short s[8]; uint4 v; } o;
#pragma unroll
        for (int k = 0; k < 8; ++k) o.s[k] = tl[c8 + k][drow];
        *(uint4*)(wvt + (((size_t)b * 512 + dx * 64 + drow) << 12) + tx * 64 + c8) = o.v;
    }
}

// ---------------------------------------------------------------------------
// MFMA windowed attention. Block = 64 tokens, 4 waves.
// ---------------------------------------------------------------------------
__global__ __launch_bounds__(256) void attn_mfma(
    const __hip_bfloat16* __restrict__ WVQ,   // [32768][1024]: 0:512=WV, 512:=Q
    const __hip_bfloat16* __restrict__ WVT,   // [8][512][4096]
    __hip_bfloat16* __restrict__ R)           // [32768][512]
{
    __shared__ __align__(16) unsigned short p_lds[64][136];  // 17408 B

    const int blk = blockIdx.x;
    const int b   = blk >> 6;
    const int t0  = (blk & 63) << 6;
    const int jmin = (t0 == 0) ? 64 : 0;
    const size_t bbase = (size_t)b << 12;
    const int tid  = threadIdx.x;
    const int lane = tid & 63;
    const int w    = tid >> 6;
    const int l15  = lane & 15;
    const int lhi  = lane >> 4;

    // ---- QK^T:  S[64][128] ----
    f32x4 acc[8] = {};
    const __hip_bfloat16* q0 =
        WVQ + ((bbase + t0 + w * 16 + l15) << 10) + 512 + lhi * 8;

    const __hip_bfloat16* brow[8];
#pragma unroll
    for (int nt = 0; nt < 8; ++nt) {
        int aj = t0 - 64 + nt * 16 + l15;
        if (aj < 0) aj = 0;                 // clamped; masked below
        brow[nt] = WVQ + ((bbase + aj) << 10) + lhi * 8;
    }

    for (int kt = 0; kt < 16; ++kt) {
        short8 qa = *(const short8*)(q0 + kt * 32);
#pragma unroll
        for (int nt = 0; nt < 8; ++nt) {
            short8 bv = *(const short8*)(brow[nt] + kt * 32);
            acc[nt] = __builtin_amdgcn_mfma_f32_16x16x32_bf16(qa, bv, acc[nt], 0, 0, 0);
        }
    }

    // ---- wave-local softmax ----
    float m4[4] = { -1e30f, -1e30f, -1e30f, -1e30f };
#pragma unroll
    for (int nt = 0; nt < 8; ++nt)
#pragma unroll
        for (int reg = 0; reg < 4; ++reg) {
            int i = w * 16 + lhi * 4 + reg;
            int j = nt * 16 + l15;
            bool valid = (j >= i) && (j <= i + 63) && (j >= jmin);
            float s = valid ? acc[nt][reg] * SCALE_F : -1e30f;
            acc[nt][reg] = s;
            m4[reg] = fmaxf(m4[reg], s);
        }
#pragma unroll
    for (int off = 8; off >= 1; off >>= 1)
#pragma unroll
        for (int reg = 0; reg < 4; ++reg)
            m4[reg] = fmaxf(m4[reg], __shfl_xor(m4[reg], off, 64));

    float sum4[4] = {};
#pragma unroll
    for (int nt = 0; nt < 8; ++nt)
#pragma unroll
        for (int reg = 0; reg < 4; ++reg) {
            float s = acc[nt][reg];
            float p = (s > -1e29f) ? __expf(s - m4[reg]) : 0.f;
            acc[nt][reg] = p;
            sum4[reg] += p;
        }
#pragma unroll
    for (int off = 8; off >= 1; off >>= 1)
#pragma unroll
        for (int reg = 0; reg < 4; ++reg)
            sum4[reg] += __shfl_xor(sum4[reg], off, 64);

    float rs4[4];
#pragma unroll
    for (int reg = 0; reg < 4; ++reg)
        rs4[reg] = (sum4[reg] > 0.f) ? 1.f / sum4[reg] : 0.f;

#pragma unroll
    for (int nt = 0; nt < 8; ++nt)
#pragma unroll
        for (int reg = 0; reg < 4; ++reg)
            p_lds[w * 16 + lhi * 4 + reg][nt * 16 + l15] =
                f2bf(acc[nt][reg] * rs4[reg]);

    __syncthreads();

    // ---- PV ----
    short8 pa[4];
#pragma unroll
    for (int kt = 0; kt < 4; ++kt)
        pa[kt] = *(const short8*)&p_lds[w * 16 + l15][kt * 32 + lhi * 8];

    int tclamp[4];
#pragma unroll
    for (int kt = 0; kt < 4; ++kt) {
        int ti = t0 - 64 + kt * 32 + lhi * 8;
        tclamp[kt] = ti < 0 ? 0 : ti;       // 8-chunks never straddle 0
    }

    const size_t vbase = (size_t)b * 512;
    for (int nt = 0; nt < 32; ++nt) {
        int d = nt * 16 + l15;
        f32x4 a = {};
#pragma unroll
        for (int kt = 0; kt < 4; ++kt) {
            short8 bv = *(const short8*)(WVT + ((vbase + d) << 12) + tclamp[kt]);
            a = __builtin_amdgcn_mfma_f32_16x16x32_bf16(pa[kt], bv, a, 0, 0, 0);
        }
        size_t rb = (bbase + t0 + w * 16 + lhi * 4) << 9;
#pragma unroll
        for (int reg = 0; reg < 4; ++reg)
            R[rb + ((size_t)reg << 9) + d] = __float2bfloat16(a[reg]);
    }
}

// ---------------------------------------------------------------------------
extern "C" void kernel_launch(void* const* d_in, const int* in_sizes, int n_in,
                              void* d_out, int out_size, void* d_ws, size_t ws_size,
                              hipStream_t stream)
{
    const float* emb   = (const float*)d_in[0];
    const float* W_wr  = (const float*)d_in[1];
    const float* b_wr  = (const float*)d_in[2];
    const float* W_qr  = (const float*)d_in[3];
    const float* b_qr  = (const float*)d_in[4];
    const float* W_out = (const float*)d_in[5];
    const float* b_out = (const float*)d_in[6];
    float* out = (float*)d_out;

    char* ws = (char*)d_ws;
    __hip_bfloat16* embb = (__hip_bfloat16*)(ws);                         // 64MB (dead after gemm1)
    __hip_bfloat16* wvt  = (__hip_bfloat16*)(ws);                         // 32MB, aliases embb
    __hip_bfloat16* wvq  = (__hip_bfloat16*)(ws + (((size_t)64) << 20));  // 64MB
    __hip_bfloat16* rbuf = (__hip_bfloat16*)(ws + (((size_t)128) << 20)); // 32MB
    __hip_bfloat16* wcat = (__hip_bfloat16*)(ws + (((size_t)160) << 20)); // 2MB
    __hip_bfloat16* wout = (__hip_bfloat16*)(ws + (((size_t)162) << 20)); // 1MB
    float*          bcat = (float*)        (ws + (((size_t)163) << 20));  // 4KB

    cast_bf16<<<dim3((MROWS * EMB / 4) / 256), dim3(256), 0, stream>>>(
        (const float4*)emb, (ushort4*)embb, MROWS * EMB / 4);
    tcast<<<dim3(2048), dim3(256), 0, stream>>>(W_wr, wcat, EMB, DM);
    tcast<<<dim3(2048), dim3(256), 0, stream>>>(W_qr, wcat + (size_t)DM * EMB, EMB, DM);
    tcast<<<dim3(2048), dim3(256), 0, stream>>>(W_out, wout, DM, EMB);
    concat_bias<<<dim3(4), dim3(256), 0, stream>>>(b_wr, b_qr, bcat);

    gemm_mfma<true><<<dim3(2048), dim3(256), 0, stream>>>(
        embb, EMB, wcat, EMB, bcat, (void*)wvq, 1024, EMB, 8);

    transpose_wv<<<dim3(64, 8, 8), dim3(256), 0, stream>>>(
        (const unsigned short*)wvq, (unsigned short*)wvt);

    attn_mfma<<<dim3(MROWS / 64), dim3(256), 0, stream>>>(wvq, wvt, rbuf);

    gemm_mfma<false><<<dim3(2048), dim3(256), 0, stream>>>(
        rbuf, DM, wout, DM, b_out, (void*)out, EMB, DM, 8);
}

// Round 5
// 276.189 us; speedup vs baseline: 8.1947x; 1.0338x over previous
//
#include <hip/hip_runtime.h>
#include <hip/hip_bf16.h>
#include <math.h>

// HashMemory: B=8, S=4096, E=1024, Dm=512, M=64 slots.
// memory at step t == write_vals of tokens [t-64, t-1]  => window-64 attention.
// Pipeline: cast emb->bf16; WVQ = emb @ [W_write|W_query] (bf16 MFMA GEMM);
// WVT = WV^T (tiled transpose); windowed attention (MFMA QK^T + wave-local
// softmax + MFMA PV); out = R @ W_out (bf16 MFMA GEMM, f32 out).
// r5: GEMMs double-buffered (T3-minimum 2-phase: stage(next) -> compute(cur)
// -> one vmcnt(0)+barrier per K-step) so staging overlaps MFMA.

#define BATCH   8
#define S_LEN   4096
#define EMB     1024
#define DM      512
#define MROWS   (BATCH * S_LEN)          // 32768
#define SCALE_F 0.04419417382415922f     // 512^-0.5

typedef __attribute__((ext_vector_type(4))) float f32x4;
typedef __attribute__((ext_vector_type(8))) short short8;

__device__ __forceinline__ unsigned short f2bf(float f) {
    __hip_bfloat16 h = __float2bfloat16(f);
    return *reinterpret_cast<unsigned short*>(&h);
}

// ---------------------------------------------------------------------------
__global__ __launch_bounds__(256) void cast_bf16(const float4* __restrict__ in,
                                                 ushort4* __restrict__ out, int n4)
{
    int id = blockIdx.x * 256 + threadIdx.x;
    if (id >= n4) return;
    float4 v = in[id];
    ushort4 o;
    o.x = f2bf(v.x); o.y = f2bf(v.y); o.z = f2bf(v.z); o.w = f2bf(v.w);
    out[id] = o;
}

__global__ __launch_bounds__(256) void tcast(const float* __restrict__ in,
                                             __hip_bfloat16* __restrict__ out,
                                             int K, int N)
{
    int id = blockIdx.x * 256 + threadIdx.x;
    if (id >= K * N) return;
    int n = id / K, k = id % K;
    out[id] = __float2bfloat16(in[k * N + n]);
}

__global__ __launch_bounds__(256) void concat_bias(const float* __restrict__ a,
                                                   const float* __restrict__ b,
                                                   float* __restrict__ out)
{
    int i = blockIdx.x * 256 + threadIdx.x;
    if (i < 512) out[i] = a[i];
    else if (i < 1024) out[i] = b[i - 512];
}

// ---------------------------------------------------------------------------
// bf16 MFMA GEMM: C[M x N] = A[M x K] @ Bt[N x K]^T + bias.
// 128x128 tile, BK=32, 256 threads (4 waves, 2x2), double-buffered LDS.
// ---------------------------------------------------------------------------
template<bool BF16OUT>
__global__ __launch_bounds__(256) void gemm_mfma(
    const __hip_bfloat16* __restrict__ A, int lda,
    const __hip_bfloat16* __restrict__ Bt, int ldb,
    const float* __restrict__ bias,
    void* __restrict__ Cv, int ldc,
    int K, int nbx)
{
    __shared__ __align__(16) char smem[32768];   // 2 x (A 8K | B 8K)

    const int nwg = gridDim.x;
    const int bid = blockIdx.x;
    const int cpx = nwg >> 3;                    // nwg divisible by 8
    const int swz = (bid & 7) * cpx + (bid >> 3);
    const int bm0 = (swz / nbx) << 7;
    const int bn0 = (swz % nbx) << 7;

    const int tid  = threadIdx.x;
    const int lane = tid & 63;
    const int w    = tid >> 6;
    const int wr   = w >> 1, wc = w & 1;
    const int rs   = lane >> 2;
    const int cs   = lane & 3;
    const int nt   = K >> 5;

    auto stage = [&](int buf, int kt) {
#pragma unroll
        for (int p = 0; p < 2; ++p) {
            int r  = p * 64 + w * 16 + rs;
            int cg = cs ^ ((r >> 1) & 3);      // inverse-swizzled SOURCE chunk
            const __hip_bfloat16* ga = A  + (size_t)(bm0 + r) * lda + kt + cg * 8;
            const __hip_bfloat16* gb = Bt + (size_t)(bn0 + r) * ldb + kt + cg * 8;
            char* la = smem + buf * 16384 +        p * 4096 + w * 1024;
            char* lb = smem + buf * 16384 + 8192 + p * 4096 + w * 1024;
            __builtin_amdgcn_global_load_lds(
                (const __attribute__((address_space(1))) unsigned int*)ga,
                (__attribute__((address_space(3))) unsigned int*)la, 16, 0, 0);
            __builtin_amdgcn_global_load_lds(
                (const __attribute__((address_space(1))) unsigned int*)gb,
                (__attribute__((address_space(3))) unsigned int*)lb, 16, 0, 0);
        }
    };

    f32x4 acc[4][4] = {};

    stage(0, 0);
    __syncthreads();            // vmcnt(0) drain: buf0 ready

    int cur = 0;
    for (int t = 0; t < nt; ++t) {
        if (t + 1 < nt) stage(cur ^ 1, (t + 1) << 5);   // loads fly under MFMA

        const char* sA = smem + cur * 16384;
        const char* sB = sA + 8192;
        short8 af[4], bfr[4];
#pragma unroll
        for (int m = 0; m < 4; ++m) {
            int r = wr * 64 + m * 16 + (lane & 15);
            int slot = (lane >> 4) ^ ((r >> 1) & 3);    // swizzled READ
            af[m] = *(const short8*)(sA + r * 64 + slot * 16);
        }
#pragma unroll
        for (int n = 0; n < 4; ++n) {
            int r = wc * 64 + n * 16 + (lane & 15);
            int slot = (lane >> 4) ^ ((r >> 1) & 3);
            bfr[n] = *(const short8*)(sB + r * 64 + slot * 16);
        }
#pragma unroll
        for (int m = 0; m < 4; ++m)
#pragma unroll
            for (int n = 0; n < 4; ++n)
                acc[m][n] = __builtin_amdgcn_mfma_f32_16x16x32_bf16(
                    af[m], bfr[n], acc[m][n], 0, 0, 0);

        __syncthreads();        // vmcnt(0)+lgkmcnt(0)+barrier: next buf ready
        cur ^= 1;
    }

    float bv[4];
#pragma unroll
    for (int n = 0; n < 4; ++n)
        bv[n] = bias[bn0 + wc * 64 + n * 16 + (lane & 15)];

#pragma unroll
    for (int m = 0; m < 4; ++m)
#pragma unroll
        for (int n = 0; n < 4; ++n)
#pragma unroll
            for (int reg = 0; reg < 4; ++reg) {
                int row = bm0 + wr * 64 + m * 16 + ((lane >> 4) << 2) + reg;
                int col = bn0 + wc * 64 + n * 16 + (lane & 15);
                float v = acc[m][n][reg] + bv[n];
                if (BF16OUT)
                    ((__hip_bfloat16*)Cv)[(size_t)row * ldc + col] = __float2bfloat16(v);
                else
                    ((float*)Cv)[(size_t)row * ldc + col] = v;
            }
}

// ---------------------------------------------------------------------------
// WV transpose: wvq[b][t][0:512] (stride 1024) -> wvt[b][d][t]
// ---------------------------------------------------------------------------
__global__ __launch_bounds__(256) void transpose_wv(
    const unsigned short* __restrict__ wvq,
    unsigned short* __restrict__ wvt)
{
    __shared__ unsigned short tl[64][66];
    const int tx  = blockIdx.x;
    const int dx  = blockIdx.y;
    const int b   = blockIdx.z;
    const int tid = threadIdx.x;
    const int r   = tid >> 3;
    const int c8  = (tid & 7) * 8;
    const size_t bbase = (size_t)b << 12;

#pragma unroll
    for (int it = 0; it < 2; ++it) {
        int row = r + it * 32;
        uint4 v = *(const uint4*)(wvq + ((bbase + tx * 64 + row) << 10) + dx * 64 + c8);
        *(unsigned*)&tl[row][c8 + 0] = v.x;
        *(unsigned*)&tl[row][c8 + 2] = v.y;
        *(unsigned*)&tl[row][c8 + 4] = v.z;
        *(unsigned*)&tl[row][c8 + 6] = v.w;
    }
    __syncthreads();
#pragma unroll
    for (int it = 0; it < 2; ++it) {
        int drow = r + it * 32;
        union { unsigned short s[8]; uint4 v; } o;
#pragma unroll
        for (int k = 0; k < 8; ++k) o.s[k] = tl[c8 + k][drow];
        *(uint4*)(wvt + (((size_t)b * 512 + dx * 64 + drow) << 12) + tx * 64 + c8) = o.v;
    }
}

// ---------------------------------------------------------------------------
// MFMA windowed attention. Block = 64 tokens, 4 waves.
// ---------------------------------------------------------------------------
__global__ __launch_bounds__(256) void attn_mfma(
    const __hip_bfloat16* __restrict__ WVQ,   // [32768][1024]: 0:512=WV, 512:=Q
    const __hip_bfloat16* __restrict__ WVT,   // [8][512][4096]
    __hip_bfloat16* __restrict__ R)           // [32768][512]
{
    __shared__ __align__(16) unsigned short p_lds[64][136];  // 17408 B

    const int blk = blockIdx.x;
    const int b   = blk >> 6;
    const int t0  = (blk & 63) << 6;
    const int jmin = (t0 == 0) ? 64 : 0;
    const size_t bbase = (size_t)b << 12;
    const int tid  = threadIdx.x;
    const int lane = tid & 63;
    const int w    = tid >> 6;
    const int l15  = lane & 15;
    const int lhi  = lane >> 4;

    // ---- QK^T:  S[64][128] ----
    f32x4 acc[8] = {};
    const __hip_bfloat16* q0 =
        WVQ + ((bbase + t0 + w * 16 + l15) << 10) + 512 + lhi * 8;

    const __hip_bfloat16* brow[8];
#pragma unroll
    for (int nt = 0; nt < 8; ++nt) {
        int aj = t0 - 64 + nt * 16 + l15;
        if (aj < 0) aj = 0;                 // clamped; masked below
        brow[nt] = WVQ + ((bbase + aj) << 10) + lhi * 8;
    }

    for (int kt = 0; kt < 16; ++kt) {
        short8 qa = *(const short8*)(q0 + kt * 32);
#pragma unroll
        for (int nt = 0; nt < 8; ++nt) {
            short8 bv = *(const short8*)(brow[nt] + kt * 32);
            acc[nt] = __builtin_amdgcn_mfma_f32_16x16x32_bf16(qa, bv, acc[nt], 0, 0, 0);
        }
    }

    // ---- wave-local softmax ----
    float m4[4] = { -1e30f, -1e30f, -1e30f, -1e30f };
#pragma unroll
    for (int nt = 0; nt < 8; ++nt)
#pragma unroll
        for (int reg = 0; reg < 4; ++reg) {
            int i = w * 16 + lhi * 4 + reg;
            int j = nt * 16 + l15;
            bool valid = (j >= i) && (j <= i + 63) && (j >= jmin);
            float s = valid ? acc[nt][reg] * SCALE_F : -1e30f;
            acc[nt][reg] = s;
            m4[reg] = fmaxf(m4[reg], s);
        }
#pragma unroll
    for (int off = 8; off >= 1; off >>= 1)
#pragma unroll
        for (int reg = 0; reg < 4; ++reg)
            m4[reg] = fmaxf(m4[reg], __shfl_xor(m4[reg], off, 64));

    float sum4[4] = {};
#pragma unroll
    for (int nt = 0; nt < 8; ++nt)
#pragma unroll
        for (int reg = 0; reg < 4; ++reg) {
            float s = acc[nt][reg];
            float p = (s > -1e29f) ? __expf(s - m4[reg]) : 0.f;
            acc[nt][reg] = p;
            sum4[reg] += p;
        }
#pragma unroll
    for (int off = 8; off >= 1; off >>= 1)
#pragma unroll
        for (int reg = 0; reg < 4; ++reg)
            sum4[reg] += __shfl_xor(sum4[reg], off, 64);

    float rs4[4];
#pragma unroll
    for (int reg = 0; reg < 4; ++reg)
        rs4[reg] = (sum4[reg] > 0.f) ? 1.f / sum4[reg] : 0.f;

#pragma unroll
    for (int nt = 0; nt < 8; ++nt)
#pragma unroll
        for (int reg = 0; reg < 4; ++reg)
            p_lds[w * 16 + lhi * 4 + reg][nt * 16 + l15] =
                f2bf(acc[nt][reg] * rs4[reg]);

    __syncthreads();

    // ---- PV ----
    short8 pa[4];
#pragma unroll
    for (int kt = 0; kt < 4; ++kt)
        pa[kt] = *(const short8*)&p_lds[w * 16 + l15][kt * 32 + lhi * 8];

    int tclamp[4];
#pragma unroll
    for (int kt = 0; kt < 4; ++kt) {
        int ti = t0 - 64 + kt * 32 + lhi * 8;
        tclamp[kt] = ti < 0 ? 0 : ti;       // 8-chunks never straddle 0
    }

    const size_t vbase = (size_t)b * 512;
    for (int nt = 0; nt < 32; ++nt) {
        int d = nt * 16 + l15;
        f32x4 a = {};
#pragma unroll
        for (int kt = 0; kt < 4; ++kt) {
            short8 bv = *(const short8*)(WVT + ((vbase + d) << 12) + tclamp[kt]);
            a = __builtin_amdgcn_mfma_f32_16x16x32_bf16(pa[kt], bv, a, 0, 0, 0);
        }
        size_t rb = (bbase + t0 + w * 16 + lhi * 4) << 9;
#pragma unroll
        for (int reg = 0; reg < 4; ++reg)
            R[rb + ((size_t)reg << 9) + d] = __float2bfloat16(a[reg]);
    }
}

// ---------------------------------------------------------------------------
extern "C" void kernel_launch(void* const* d_in, const int* in_sizes, int n_in,
                              void* d_out, int out_size, void* d_ws, size_t ws_size,
                              hipStream_t stream)
{
    const float* emb   = (const float*)d_in[0];
    const float* W_wr  = (const float*)d_in[1];
    const float* b_wr  = (const float*)d_in[2];
    const float* W_qr  = (const float*)d_in[3];
    const float* b_qr  = (const float*)d_in[4];
    const float* W_out = (const float*)d_in[5];
    const float* b_out = (const float*)d_in[6];
    float* out = (float*)d_out;

    char* ws = (char*)d_ws;
    __hip_bfloat16* embb = (__hip_bfloat16*)(ws);                         // 64MB (dead after gemm1)
    __hip_bfloat16* wvt  = (__hip_bfloat16*)(ws);                         // 32MB, aliases embb
    __hip_bfloat16* wvq  = (__hip_bfloat16*)(ws + (((size_t)64) << 20));  // 64MB
    __hip_bfloat16* rbuf = (__hip_bfloat16*)(ws + (((size_t)128) << 20)); // 32MB
    __hip_bfloat16* wcat = (__hip_bfloat16*)(ws + (((size_t)160) << 20)); // 2MB
    __hip_bfloat16* wout = (__hip_bfloat16*)(ws + (((size_t)162) << 20)); // 1MB
    float*          bcat = (float*)        (ws + (((size_t)163) << 20));  // 4KB

    cast_bf16<<<dim3((MROWS * EMB / 4) / 256), dim3(256), 0, stream>>>(
        (const float4*)emb, (ushort4*)embb, MROWS * EMB / 4);
    tcast<<<dim3(2048), dim3(256), 0, stream>>>(W_wr, wcat, EMB, DM);
    tcast<<<dim3(2048), dim3(256), 0, stream>>>(W_qr, wcat + (size_t)DM * EMB, EMB, DM);
    tcast<<<dim3(2048), dim3(256), 0, stream>>>(W_out, wout, DM, EMB);
    concat_bias<<<dim3(4), dim3(256), 0, stream>>>(b_wr, b_qr, bcat);

    gemm_mfma<true><<<dim3(2048), dim3(256), 0, stream>>>(
        embb, EMB, wcat, EMB, bcat, (void*)wvq, 1024, EMB, 8);

    transpose_wv<<<dim3(64, 8, 8), dim3(256), 0, stream>>>(
        (const unsigned short*)wvq, (unsigned short*)wvt);

    attn_mfma<<<dim3(MROWS / 64), dim3(256), 0, stream>>>(wvq, wvt, rbuf);

    gemm_mfma<false><<<dim3(2048), dim3(256), 0, stream>>>(
        rbuf, DM, wout, DM, b_out, (void*)out, EMB, DM, 8);
}

// Round 7
// 268.694 us; speedup vs baseline: 8.4233x; 1.0279x over previous
//
#include <hip/hip_runtime.h>
#include <hip/hip_bf16.h>
#include <math.h>

// HashMemory: B=8, S=4096, E=1024, Dm=512, M=64 slots.
// memory at step t == write_vals of tokens [t-64, t-1]  => window-64 attention.
// Pipeline: cast emb->bf16; WVQ = emb @ [W_write|W_query] (bf16 MFMA GEMM);
// WVT = WV^T (tiled transpose); windowed attention (MFMA QK^T + wave-local
// softmax + MFMA PV); out = R @ W_out (bf16 MFMA GEMM, f32 out).
// r7: fix r6's tail race — counted vmcnt(4) only valid while stage(t+2) was
// issued; epilogue iterations must drain with vmcnt(0).

#define BATCH   8
#define S_LEN   4096
#define EMB     1024
#define DM      512
#define MROWS   (BATCH * S_LEN)          // 32768
#define SCALE_F 0.04419417382415922f     // 512^-0.5

typedef __attribute__((ext_vector_type(4))) float f32x4;
typedef __attribute__((ext_vector_type(8))) short short8;

__device__ __forceinline__ unsigned short f2bf(float f) {
    __hip_bfloat16 h = __float2bfloat16(f);
    return *reinterpret_cast<unsigned short*>(&h);
}

// ---------------------------------------------------------------------------
__global__ __launch_bounds__(256) void cast_bf16(const float4* __restrict__ in,
                                                 ushort4* __restrict__ out, int n4)
{
    int id = blockIdx.x * 256 + threadIdx.x;
    if (id >= n4) return;
    float4 v = in[id];
    ushort4 o;
    o.x = f2bf(v.x); o.y = f2bf(v.y); o.z = f2bf(v.z); o.w = f2bf(v.w);
    out[id] = o;
}

__global__ __launch_bounds__(256) void tcast(const float* __restrict__ in,
                                             __hip_bfloat16* __restrict__ out,
                                             int K, int N)
{
    int id = blockIdx.x * 256 + threadIdx.x;
    if (id >= K * N) return;
    int n = id / K, k = id % K;
    out[id] = __float2bfloat16(in[k * N + n]);
}

__global__ __launch_bounds__(256) void concat_bias(const float* __restrict__ a,
                                                   const float* __restrict__ b,
                                                   float* __restrict__ out)
{
    int i = blockIdx.x * 256 + threadIdx.x;
    if (i < 512) out[i] = a[i];
    else if (i < 1024) out[i] = b[i - 512];
}

// ---------------------------------------------------------------------------
// bf16 MFMA GEMM: C[M x N] = A[M x K] @ Bt[N x K]^T + bias.
// 128x128 tile, BK=32, 256 threads (4 waves, 2x2).
// Depth-2 pipeline: 3 LDS buffers; per K-tile issue stage(t+2), compute
// buf[t%3], then counted wait: vmcnt(4) while prefetching, vmcnt(0) in tail.
// ---------------------------------------------------------------------------
template<bool BF16OUT>
__global__ __launch_bounds__(256) void gemm_mfma(
    const __hip_bfloat16* __restrict__ A, int lda,
    const __hip_bfloat16* __restrict__ Bt, int ldb,
    const float* __restrict__ bias,
    void* __restrict__ Cv, int ldc,
    int K, int nbx)
{
    __shared__ __align__(16) char smem[49152];   // 3 x (A 8K | B 8K)

    const int nwg = gridDim.x;
    const int bid = blockIdx.x;
    const int cpx = nwg >> 3;                    // nwg divisible by 8
    const int swz = (bid & 7) * cpx + (bid >> 3);
    const int bm0 = (swz / nbx) << 7;
    const int bn0 = (swz % nbx) << 7;

    const int tid  = threadIdx.x;
    const int lane = tid & 63;
    const int w    = tid >> 6;
    const int wr   = w >> 1, wc = w & 1;
    const int rs   = lane >> 2;
    const int cs   = lane & 3;
    const int nt   = K >> 5;

    auto stage = [&](int buf, int kt) {          // 4 gload_lds per thread
#pragma unroll
        for (int p = 0; p < 2; ++p) {
            int r  = p * 64 + w * 16 + rs;
            int cg = cs ^ ((r >> 1) & 3);        // inverse-swizzled SOURCE chunk
            const __hip_bfloat16* ga = A  + (size_t)(bm0 + r) * lda + kt + cg * 8;
            const __hip_bfloat16* gb = Bt + (size_t)(bn0 + r) * ldb + kt + cg * 8;
            char* la = smem + buf * 16384 +        p * 4096 + w * 1024;
            char* lb = smem + buf * 16384 + 8192 + p * 4096 + w * 1024;
            __builtin_amdgcn_global_load_lds(
                (const __attribute__((address_space(1))) unsigned int*)ga,
                (__attribute__((address_space(3))) unsigned int*)la, 16, 0, 0);
            __builtin_amdgcn_global_load_lds(
                (const __attribute__((address_space(1))) unsigned int*)gb,
                (__attribute__((address_space(3))) unsigned int*)lb, 16, 0, 0);
        }
    };

    f32x4 acc[4][4] = {};

    stage(0, 0);
    stage(1, 32);                                // K >= 64 always here
    asm volatile("s_waitcnt vmcnt(4)" ::: "memory");  // tile0 landed
    __builtin_amdgcn_s_barrier();

    for (int t = 0; t < nt; ++t) {
        const int cur = t % 3;
        const bool pf = (t + 2 < nt);
        if (pf) stage((t + 2) % 3, (t + 2) << 5);   // fly under MFMA

        const char* sA = smem + cur * 16384;
        const char* sB = sA + 8192;
        short8 af[4], bfr[4];
#pragma unroll
        for (int m = 0; m < 4; ++m) {
            int r = wr * 64 + m * 16 + (lane & 15);
            int slot = (lane >> 4) ^ ((r >> 1) & 3);    // swizzled READ
            af[m] = *(const short8*)(sA + r * 64 + slot * 16);
        }
#pragma unroll
        for (int n = 0; n < 4; ++n) {
            int r = wc * 64 + n * 16 + (lane & 15);
            int slot = (lane >> 4) ^ ((r >> 1) & 3);
            bfr[n] = *(const short8*)(sB + r * 64 + slot * 16);
        }
#pragma unroll
        for (int m = 0; m < 4; ++m)
#pragma unroll
            for (int n = 0; n < 4; ++n)
                acc[m][n] = __builtin_amdgcn_mfma_f32_16x16x32_bf16(
                    af[m], bfr[n], acc[m][n], 0, 0, 0);

        // While prefetching: leave t+2's 4 loads in flight, ensure t+1's
        // landed (8 outstanding -> vmcnt(4)). Once staging stops, only
        // t+1's (<=4) are outstanding -> must drain fully: vmcnt(0).
        if (pf) { asm volatile("s_waitcnt vmcnt(4)" ::: "memory"); }
        else    { asm volatile("s_waitcnt vmcnt(0)" ::: "memory"); }
        __builtin_amdgcn_s_barrier();
    }

    float bv[4];
#pragma unroll
    for (int n = 0; n < 4; ++n)
        bv[n] = bias[bn0 + wc * 64 + n * 16 + (lane & 15)];

#pragma unroll
    for (int m = 0; m < 4; ++m)
#pragma unroll
        for (int n = 0; n < 4; ++n)
#pragma unroll
            for (int reg = 0; reg < 4; ++reg) {
                int row = bm0 + wr * 64 + m * 16 + ((lane >> 4) << 2) + reg;
                int col = bn0 + wc * 64 + n * 16 + (lane & 15);
                float v = acc[m][n][reg] + bv[n];
                if (BF16OUT)
                    ((__hip_bfloat16*)Cv)[(size_t)row * ldc + col] = __float2bfloat16(v);
                else
                    ((float*)Cv)[(size_t)row * ldc + col] = v;
            }
}

// ---------------------------------------------------------------------------
// WV transpose: wvq[b][t][0:512] (stride 1024) -> wvt[b][d][t]
// ---------------------------------------------------------------------------
__global__ __launch_bounds__(256) void transpose_wv(
    const unsigned short* __restrict__ wvq,
    unsigned short* __restrict__ wvt)
{
    __shared__ unsigned short tl[64][66];
    const int tx  = blockIdx.x;
    const int dx  = blockIdx.y;
    const int b   = blockIdx.z;
    const int tid = threadIdx.x;
    const int r   = tid >> 3;
    const int c8  = (tid & 7) * 8;
    const size_t bbase = (size_t)b << 12;

#pragma unroll
    for (int it = 0; it < 2; ++it) {
        int row = r + it * 32;
        uint4 v = *(const uint4*)(wvq + ((bbase + tx * 64 + row) << 10) + dx * 64 + c8);
        *(unsigned*)&tl[row][c8 + 0] = v.x;
        *(unsigned*)&tl[row][c8 + 2] = v.y;
        *(unsigned*)&tl[row][c8 + 4] = v.z;
        *(unsigned*)&tl[row][c8 + 6] = v.w;
    }
    __syncthreads();
#pragma unroll
    for (int it = 0; it < 2; ++it) {
        int drow = r + it * 32;
        union { unsigned short s[8]; uint4 v; } o;
#pragma unroll
        for (int k = 0; k < 8; ++k) o.s[k] = tl[c8 + k][drow];
        *(uint4*)(wvt + (((size_t)b * 512 + dx * 64 + drow) << 12) + tx * 64 + c8) = o.v;
    }
}

// ---------------------------------------------------------------------------
// MFMA windowed attention. Block = 64 tokens, 4 waves.
// ---------------------------------------------------------------------------
__global__ __launch_bounds__(256) void attn_mfma(
    const __hip_bfloat16* __restrict__ WVQ,   // [32768][1024]: 0:512=WV, 512:=Q
    const __hip_bfloat16* __restrict__ WVT,   // [8][512][4096]
    __hip_bfloat16* __restrict__ R)           // [32768][512]
{
    __shared__ __align__(16) unsigned short p_lds[64][136];  // 17408 B

    const int blk = blockIdx.x;
    const int b   = blk >> 6;
    const int t0  = (blk & 63) << 6;
    const int jmin = (t0 == 0) ? 64 : 0;
    const size_t bbase = (size_t)b << 12;
    const int tid  = threadIdx.x;
    const int lane = tid & 63;
    const int w    = tid >> 6;
    const int l15  = lane & 15;
    const int lhi  = lane >> 4;

    // ---- QK^T:  S[64][128] ----
    f32x4 acc[8] = {};
    const __hip_bfloat16* q0 =
        WVQ + ((bbase + t0 + w * 16 + l15) << 10) + 512 + lhi * 8;

    const __hip_bfloat16* brow[8];
#pragma unroll
    for (int nt = 0; nt < 8; ++nt) {
        int aj = t0 - 64 + nt * 16 + l15;
        if (aj < 0) aj = 0;                 // clamped; masked below
        brow[nt] = WVQ + ((bbase + aj) << 10) + lhi * 8;
    }

    for (int kt = 0; kt < 16; ++kt) {
        short8 qa = *(const short8*)(q0 + kt * 32);
#pragma unroll
        for (int nt = 0; nt < 8; ++nt) {
            short8 bv = *(const short8*)(brow[nt] + kt * 32);
            acc[nt] = __builtin_amdgcn_mfma_f32_16x16x32_bf16(qa, bv, acc[nt], 0, 0, 0);
        }
    }

    // ---- wave-local softmax ----
    float m4[4] = { -1e30f, -1e30f, -1e30f, -1e30f };
#pragma unroll
    for (int nt = 0; nt < 8; ++nt)
#pragma unroll
        for (int reg = 0; reg < 4; ++reg) {
            int i = w * 16 + lhi * 4 + reg;
            int j = nt * 16 + l15;
            bool valid = (j >= i) && (j <= i + 63) && (j >= jmin);
            float s = valid ? acc[nt][reg] * SCALE_F : -1e30f;
            acc[nt][reg] = s;
            m4[reg] = fmaxf(m4[reg], s);
        }
#pragma unroll
    for (int off = 8; off >= 1; off >>= 1)
#pragma unroll
        for (int reg = 0; reg < 4; ++reg)
            m4[reg] = fmaxf(m4[reg], __shfl_xor(m4[reg], off, 64));

    float sum4[4] = {};
#pragma unroll
    for (int nt = 0; nt < 8; ++nt)
#pragma unroll
        for (int reg = 0; reg < 4; ++reg) {
            float s = acc[nt][reg];
            float p = (s > -1e29f) ? __expf(s - m4[reg]) : 0.f;
            acc[nt][reg] = p;
            sum4[reg] += p;
        }
#pragma unroll
    for (int off = 8; off >= 1; off >>= 1)
#pragma unroll
        for (int reg = 0; reg < 4; ++reg)
            sum4[reg] += __shfl_xor(sum4[reg], off, 64);

    float rs4[4];
#pragma unroll
    for (int reg = 0; reg < 4; ++reg)
        rs4[reg] = (sum4[reg] > 0.f) ? 1.f / sum4[reg] : 0.f;

#pragma unroll
    for (int nt = 0; nt < 8; ++nt)
#pragma unroll
        for (int reg = 0; reg < 4; ++reg)
            p_lds[w * 16 + lhi * 4 + reg][nt * 16 + l15] =
                f2bf(acc[nt][reg] * rs4[reg]);

    __syncthreads();

    // ---- PV ----
    short8 pa[4];
#pragma unroll
    for (int kt = 0; kt < 4; ++kt)
        pa[kt] = *(const short8*)&p_lds[w * 16 + l15][kt * 32 + lhi * 8];

    int tclamp[4];
#pragma unroll
    for (int kt = 0; kt < 4; ++kt) {
        int ti = t0 - 64 + kt * 32 + lhi * 8;
        tclamp[kt] = ti < 0 ? 0 : ti;       // 8-chunks never straddle 0
    }

    const size_t vbase = (size_t)b * 512;
    for (int nt = 0; nt < 32; ++nt) {
        int d = nt * 16 + l15;
        f32x4 a = {};
#pragma unroll
        for (int kt = 0; kt < 4; ++kt) {
            short8 bv = *(const short8*)(WVT + ((vbase + d) << 12) + tclamp[kt]);
            a = __builtin_amdgcn_mfma_f32_16x16x32_bf16(pa[kt], bv, a, 0, 0, 0);
        }
        size_t rb = (bbase + t0 + w * 16 + lhi * 4) << 9;
#pragma unroll
        for (int reg = 0; reg < 4; ++reg)
            R[rb + ((size_t)reg << 9) + d] = __float2bfloat16(a[reg]);
    }
}

// ---------------------------------------------------------------------------
extern "C" void kernel_launch(void* const* d_in, const int* in_sizes, int n_in,
                              void* d_out, int out_size, void* d_ws, size_t ws_size,
                              hipStream_t stream)
{
    const float* emb   = (const float*)d_in[0];
    const float* W_wr  = (const float*)d_in[1];
    const float* b_wr  = (const float*)d_in[2];
    const float* W_qr  = (const float*)d_in[3];
    const float* b_qr  = (const float*)d_in[4];
    const float* W_out = (const float*)d_in[5];
    const float* b_out = (const float*)d_in[6];
    float* out = (float*)d_out;

    char* ws = (char*)d_ws;
    __hip_bfloat16* embb = (__hip_bfloat16*)(ws);                         // 64MB (dead after gemm1)
    __hip_bfloat16* wvt  = (__hip_bfloat16*)(ws);                         // 32MB, aliases embb
    __hip_bfloat16* wvq  = (__hip_bfloat16*)(ws + (((size_t)64) << 20));  // 64MB
    __hip_bfloat16* rbuf = (__hip_bfloat16*)(ws + (((size_t)128) << 20)); // 32MB
    __hip_bfloat16* wcat = (__hip_bfloat16*)(ws + (((size_t)160) << 20)); // 2MB
    __hip_bfloat16* wout = (__hip_bfloat16*)(ws + (((size_t)162) << 20)); // 1MB
    float*          bcat = (float*)        (ws + (((size_t)163) << 20));  // 4KB

    cast_bf16<<<dim3((MROWS * EMB / 4) / 256), dim3(256), 0, stream>>>(
        (const float4*)emb, (ushort4*)embb, MROWS * EMB / 4);
    tcast<<<dim3(2048), dim3(256), 0, stream>>>(W_wr, wcat, EMB, DM);
    tcast<<<dim3(2048), dim3(256), 0, stream>>>(W_qr, wcat + (size_t)DM * EMB, EMB, DM);
    tcast<<<dim3(2048), dim3(256), 0, stream>>>(W_out, wout, DM, EMB);
    concat_bias<<<dim3(4), dim3(256), 0, stream>>>(b_wr, b_qr, bcat);

    gemm_mfma<true><<<dim3(2048), dim3(256), 0, stream>>>(
        embb, EMB, wcat, EMB, bcat, (void*)wvq, 1024, EMB, 8);

    transpose_wv<<<dim3(64, 8, 8), dim3(256), 0, stream>>>(
        (const unsigned short*)wvq, (unsigned short*)wvt);

    attn_mfma<<<dim3(MROWS / 64), dim3(256), 0, stream>>>(wvq, wvt, rbuf);

    gemm_mfma<false><<<dim3(2048), dim3(256), 0, stream>>>(
        rbuf, DM, wout, DM, b_out, (void*)out, EMB, DM, 8);
}

// Round 8
// 250.553 us; speedup vs baseline: 9.0332x; 1.0724x over previous
//
#include <hip/hip_runtime.h>
#include <hip/hip_bf16.h>
#include <math.h>

// HashMemory: B=8, S=4096, E=1024, Dm=512, M=64 slots.
// memory at step t == write_vals of tokens [t-64, t-1]  => window-64 attention.
// Pipeline: cast emb->bf16; WVQ = emb @ [W_write|W_query] (bf16 MFMA GEMM);
// WVT = WV^T (tiled transpose); windowed attention (MFMA QK^T + wave-local
// softmax + MFMA PV); out = R @ W_out (bf16 MFMA GEMM, f32 out).
// r8: GEMMs -> 256x256 tile, BK=64, 8 waves (2x4), 128KB double-buffered LDS,
// stage whole next tile at K-tile start, 4 quadrant phases, ONE barrier/K-tile.

#define BATCH   8
#define S_LEN   4096
#define EMB     1024
#define DM      512
#define MROWS   (BATCH * S_LEN)          // 32768
#define SCALE_F 0.04419417382415922f     // 512^-0.5

typedef __attribute__((ext_vector_type(4))) float f32x4;
typedef __attribute__((ext_vector_type(8))) short short8;

__device__ __forceinline__ unsigned short f2bf(float f) {
    __hip_bfloat16 h = __float2bfloat16(f);
    return *reinterpret_cast<unsigned short*>(&h);
}

// ---------------------------------------------------------------------------
__global__ __launch_bounds__(256) void cast_bf16(const float4* __restrict__ in,
                                                 ushort4* __restrict__ out, int n4)
{
    int id = blockIdx.x * 256 + threadIdx.x;
    if (id >= n4) return;
    float4 v = in[id];
    ushort4 o;
    o.x = f2bf(v.x); o.y = f2bf(v.y); o.z = f2bf(v.z); o.w = f2bf(v.w);
    out[id] = o;
}

__global__ __launch_bounds__(256) void tcast(const float* __restrict__ in,
                                             __hip_bfloat16* __restrict__ out,
                                             int K, int N)
{
    int id = blockIdx.x * 256 + threadIdx.x;
    if (id >= K * N) return;
    int n = id / K, k = id % K;
    out[id] = __float2bfloat16(in[k * N + n]);
}

__global__ __launch_bounds__(256) void concat_bias(const float* __restrict__ a,
                                                   const float* __restrict__ b,
                                                   float* __restrict__ out)
{
    int i = blockIdx.x * 256 + threadIdx.x;
    if (i < 512) out[i] = a[i];
    else if (i < 1024) out[i] = b[i - 512];
}

// ---------------------------------------------------------------------------
// bf16 MFMA GEMM, 256x256 tile: C[M x N] = A[M x K] @ Bt[N x K]^T + bias.
// 512 threads = 8 waves (2x4); per-wave output 128x64; BK=64.
// LDS: [buf][A 32K | B 32K] x2 = 128KB. Rows 128B, chunk swizzle ^(row&7).
// Per K-tile: stage next tile (8 gload_lds), 4 quadrant phases, 1 barrier.
// ---------------------------------------------------------------------------
template<bool BF16OUT>
__global__ __launch_bounds__(512, 2) void gemm256(
    const __hip_bfloat16* __restrict__ A, int lda,
    const __hip_bfloat16* __restrict__ Bt, int ldb,
    const float* __restrict__ bias,
    void* __restrict__ Cv, int ldc,
    int K, int nbx)
{
    __shared__ __align__(16) char smem[131072];

    const int nwg = gridDim.x;
    const int bid = blockIdx.x;
    const int cpx = nwg >> 3;                    // nwg divisible by 8
    const int swz = (bid & 7) * cpx + (bid >> 3);
    const int bm0 = (swz / nbx) << 8;
    const int bn0 = (swz % nbx) << 8;

    const int tid  = threadIdx.x;
    const int lane = tid & 63;
    const int w    = tid >> 6;                   // 0..7
    const int wm   = w >> 2, wn = w & 3;         // 2x4 wave grid
    const int l15  = lane & 15, lhi = lane >> 4;
    const int nt   = K >> 6;

    // staging: slot s = i*512 + tid covers row_in_half = s>>3, phys chunk s&7.
    // stored-with-swizzle => global source chunk = phys ^ (row&7).
    const int srow  = w * 8 + (lane >> 3);                 // 0..63 (+i*64)
    const int scol8 = (((lane & 7) ^ (lane >> 3)) << 3);   // bf16 col in [0,64)

    auto stage_tile = [&](int buf, int kt) {
#pragma unroll
        for (int h = 0; h < 4; ++h) {            // 0=A0 1=A1 2=B0 3=B1
            const int isB = h >> 1, hh = h & 1;
            const __hip_bfloat16* G = isB ? Bt : A;
            const int ldg = isB ? ldb : lda;
            const int rb  = (isB ? bn0 : bm0) + hh * 128;
#pragma unroll
            for (int i = 0; i < 2; ++i) {
                const __hip_bfloat16* g =
                    G + (size_t)(rb + i * 64 + srow) * ldg + kt + scol8;
                char* l = smem + buf * 65536 + isB * 32768 + hh * 16384
                          + i * 8192 + w * 1024;      // wave-uniform; HW adds lane*16
                __builtin_amdgcn_global_load_lds(
                    (const __attribute__((address_space(1))) unsigned int*)g,
                    (__attribute__((address_space(3))) unsigned int*)l, 16, 0, 0);
            }
        }
    };

    f32x4 acc[8][4] = {};    // [M-frag: (>>2)*64+(&3)*16][N-frag: (>>1)*32+(&1)*16]

    stage_tile(0, 0);
    __syncthreads();

    for (int t = 0; t < nt; ++t) {
        const int cur = t & 1;
        if (t + 1 < nt) stage_tile(cur ^ 1, (t + 1) << 6);  // fly under 4 phases

        const char* sA = smem + cur * 65536;
        const char* sB = sA + 32768;

#pragma unroll
        for (int q = 0; q < 4; ++q) {            // quadrant (mh, nh)
            const int mh = q >> 1, nh = q & 1;
            short8 af[4][2], bfv[2][2];
#pragma unroll
            for (int mi = 0; mi < 4; ++mi) {
                const int r = wm * 128 + mh * 64 + mi * 16 + l15;
#pragma unroll
                for (int kk = 0; kk < 2; ++kk) {
                    const int pc = (kk * 4 + lhi) ^ (r & 7);
                    af[mi][kk] = *(const short8*)(sA + r * 128 + (pc << 4));
                }
            }
#pragma unroll
            for (int ni = 0; ni < 2; ++ni) {
                const int r = wn * 64 + nh * 32 + ni * 16 + l15;
#pragma unroll
                for (int kk = 0; kk < 2; ++kk) {
                    const int pc = (kk * 4 + lhi) ^ (r & 7);
                    bfv[ni][kk] = *(const short8*)(sB + r * 128 + (pc << 4));
                }
            }
#pragma unroll
            for (int mi = 0; mi < 4; ++mi)
#pragma unroll
                for (int ni = 0; ni < 2; ++ni)
#pragma unroll
                    for (int kk = 0; kk < 2; ++kk)
                        acc[mh * 4 + mi][nh * 2 + ni] =
                            __builtin_amdgcn_mfma_f32_16x16x32_bf16(
                                af[mi][kk], bfv[ni][kk],
                                acc[mh * 4 + mi][nh * 2 + ni], 0, 0, 0);
        }
        __syncthreads();     // drains tile t+1's stages; frees buf cur for t+2
    }

    // ---- epilogue ----
    float bv[4];
#pragma unroll
    for (int N = 0; N < 4; ++N)
        bv[N] = bias[bn0 + wn * 64 + (N >> 1) * 32 + (N & 1) * 16 + l15];

#pragma unroll
    for (int M = 0; M < 8; ++M)
#pragma unroll
        for (int N = 0; N < 4; ++N)
#pragma unroll
            for (int reg = 0; reg < 4; ++reg) {
                int row = bm0 + wm * 128 + (M >> 2) * 64 + (M & 3) * 16
                          + lhi * 4 + reg;
                int col = bn0 + wn * 64 + (N >> 1) * 32 + (N & 1) * 16 + l15;
                float v = acc[M][N][reg] + bv[N];
                if (BF16OUT)
                    ((__hip_bfloat16*)Cv)[(size_t)row * ldc + col] = __float2bfloat16(v);
                else
                    ((float*)Cv)[(size_t)row * ldc + col] = v;
            }
}

// ---------------------------------------------------------------------------
// WV transpose: wvq[b][t][0:512] (stride 1024) -> wvt[b][d][t]
// ---------------------------------------------------------------------------
__global__ __launch_bounds__(256) void transpose_wv(
    const unsigned short* __restrict__ wvq,
    unsigned short* __restrict__ wvt)
{
    __shared__ unsigned short tl[64][66];
    const int tx  = blockIdx.x;
    const int dx  = blockIdx.y;
    const int b   = blockIdx.z;
    const int tid = threadIdx.x;
    const int r   = tid >> 3;
    const int c8  = (tid & 7) * 8;
    const size_t bbase = (size_t)b << 12;

#pragma unroll
    for (int it = 0; it < 2; ++it) {
        int row = r + it * 32;
        uint4 v = *(const uint4*)(wvq + ((bbase + tx * 64 + row) << 10) + dx * 64 + c8);
        *(unsigned*)&tl[row][c8 + 0] = v.x;
        *(unsigned*)&tl[row][c8 + 2] = v.y;
        *(unsigned*)&tl[row][c8 + 4] = v.z;
        *(unsigned*)&tl[row][c8 + 6] = v.w;
    }
    __syncthreads();
#pragma unroll
    for (int it = 0; it < 2; ++it) {
        int drow = r + it * 32;
        union { unsigned short s[8]; uint4 v; } o;
#pragma unroll
        for (int k = 0; k < 8; ++k) o.s[k] = tl[c8 + k][drow];
        *(uint4*)(wvt + (((size_t)b * 512 + dx * 64 + drow) << 12) + tx * 64 + c8) = o.v;
    }
}

// ---------------------------------------------------------------------------
// MFMA windowed attention. Block = 64 tokens, 4 waves.
// ---------------------------------------------------------------------------
__global__ __launch_bounds__(256) void attn_mfma(
    const __hip_bfloat16* __restrict__ WVQ,   // [32768][1024]: 0:512=WV, 512:=Q
    const __hip_bfloat16* __restrict__ WVT,   // [8][512][4096]
    __hip_bfloat16* __restrict__ R)           // [32768][512]
{
    __shared__ __align__(16) unsigned short p_lds[64][136];  // 17408 B

    const int blk = blockIdx.x;
    const int b   = blk >> 6;
    const int t0  = (blk & 63) << 6;
    const int jmin = (t0 == 0) ? 64 : 0;
    const size_t bbase = (size_t)b << 12;
    const int tid  = threadIdx.x;
    const int lane = tid & 63;
    const int w    = tid >> 6;
    const int l15  = lane & 15;
    const int lhi  = lane >> 4;

    // ---- QK^T:  S[64][128] ----
    f32x4 acc[8] = {};
    const __hip_bfloat16* q0 =
        WVQ + ((bbase + t0 + w * 16 + l15) << 10) + 512 + lhi * 8;

    const __hip_bfloat16* brow[8];
#pragma unroll
    for (int nt = 0; nt < 8; ++nt) {
        int aj = t0 - 64 + nt * 16 + l15;
        if (aj < 0) aj = 0;                 // clamped; masked below
        brow[nt] = WVQ + ((bbase + aj) << 10) + lhi * 8;
    }

    for (int kt = 0; kt < 16; ++kt) {
        short8 qa = *(const short8*)(q0 + kt * 32);
#pragma unroll
        for (int nt = 0; nt < 8; ++nt) {
            short8 bv = *(const short8*)(brow[nt] + kt * 32);
            acc[nt] = __builtin_amdgcn_mfma_f32_16x16x32_bf16(qa, bv, acc[nt], 0, 0, 0);
        }
    }

    // ---- wave-local softmax ----
    float m4[4] = { -1e30f, -1e30f, -1e30f, -1e30f };
#pragma unroll
    for (int nt = 0; nt < 8; ++nt)
#pragma unroll
        for (int reg = 0; reg < 4; ++reg) {
            int i = w * 16 + lhi * 4 + reg;
            int j = nt * 16 + l15;
            bool valid = (j >= i) && (j <= i + 63) && (j >= jmin);
            float s = valid ? acc[nt][reg] * SCALE_F : -1e30f;
            acc[nt][reg] = s;
            m4[reg] = fmaxf(m4[reg], s);
        }
#pragma unroll
    for (int off = 8; off >= 1; off >>= 1)
#pragma unroll
        for (int reg = 0; reg < 4; ++reg)
            m4[reg] = fmaxf(m4[reg], __shfl_xor(m4[reg], off, 64));

    float sum4[4] = {};
#pragma unroll
    for (int nt = 0; nt < 8; ++nt)
#pragma unroll
        for (int reg = 0; reg < 4; ++reg) {
            float s = acc[nt][reg];
            float p = (s > -1e29f) ? __expf(s - m4[reg]) : 0.f;
            acc[nt][reg] = p;
            sum4[reg] += p;
        }
#pragma unroll
    for (int off = 8; off >= 1; off >>= 1)
#pragma unroll
        for (int reg = 0; reg < 4; ++reg)
            sum4[reg] += __shfl_xor(sum4[reg], off, 64);

    float rs4[4];
#pragma unroll
    for (int reg = 0; reg < 4; ++reg)
        rs4[reg] = (sum4[reg] > 0.f) ? 1.f / sum4[reg] : 0.f;

#pragma unroll
    for (int nt = 0; nt < 8; ++nt)
#pragma unroll
        for (int reg = 0; reg < 4; ++reg)
            p_lds[w * 16 + lhi * 4 + reg][nt * 16 + l15] =
                f2bf(acc[nt][reg] * rs4[reg]);

    __syncthreads();

    // ---- PV ----
    short8 pa[4];
#pragma unroll
    for (int kt = 0; kt < 4; ++kt)
        pa[kt] = *(const short8*)&p_lds[w * 16 + l15][kt * 32 + lhi * 8];

    int tclamp[4];
#pragma unroll
    for (int kt = 0; kt < 4; ++kt) {
        int ti = t0 - 64 + kt * 32 + lhi * 8;
        tclamp[kt] = ti < 0 ? 0 : ti;       // 8-chunks never straddle 0
    }

    const size_t vbase = (size_t)b * 512;
    for (int nt = 0; nt < 32; ++nt) {
        int d = nt * 16 + l15;
        f32x4 a = {};
#pragma unroll
        for (int kt = 0; kt < 4; ++kt) {
            short8 bv = *(const short8*)(WVT + ((vbase + d) << 12) + tclamp[kt]);
            a = __builtin_amdgcn_mfma_f32_16x16x32_bf16(pa[kt], bv, a, 0, 0, 0);
        }
        size_t rb = (bbase + t0 + w * 16 + lhi * 4) << 9;
#pragma unroll
        for (int reg = 0; reg < 4; ++reg)
            R[rb + ((size_t)reg << 9) + d] = __float2bfloat16(a[reg]);
    }
}

// ---------------------------------------------------------------------------
extern "C" void kernel_launch(void* const* d_in, const int* in_sizes, int n_in,
                              void* d_out, int out_size, void* d_ws, size_t ws_size,
                              hipStream_t stream)
{
    const float* emb   = (const float*)d_in[0];
    const float* W_wr  = (const float*)d_in[1];
    const float* b_wr  = (const float*)d_in[2];
    const float* W_qr  = (const float*)d_in[3];
    const float* b_qr  = (const float*)d_in[4];
    const float* W_out = (const float*)d_in[5];
    const float* b_out = (const float*)d_in[6];
    float* out = (float*)d_out;

    char* ws = (char*)d_ws;
    __hip_bfloat16* embb = (__hip_bfloat16*)(ws);                         // 64MB (dead after gemm1)
    __hip_bfloat16* wvt  = (__hip_bfloat16*)(ws);                         // 32MB, aliases embb
    __hip_bfloat16* wvq  = (__hip_bfloat16*)(ws + (((size_t)64) << 20));  // 64MB
    __hip_bfloat16* rbuf = (__hip_bfloat16*)(ws + (((size_t)128) << 20)); // 32MB
    __hip_bfloat16* wcat = (__hip_bfloat16*)(ws + (((size_t)160) << 20)); // 2MB
    __hip_bfloat16* wout = (__hip_bfloat16*)(ws + (((size_t)162) << 20)); // 1MB
    float*          bcat = (float*)        (ws + (((size_t)163) << 20));  // 4KB

    cast_bf16<<<dim3((MROWS * EMB / 4) / 256), dim3(256), 0, stream>>>(
        (const float4*)emb, (ushort4*)embb, MROWS * EMB / 4);
    tcast<<<dim3(2048), dim3(256), 0, stream>>>(W_wr, wcat, EMB, DM);
    tcast<<<dim3(2048), dim3(256), 0, stream>>>(W_qr, wcat + (size_t)DM * EMB, EMB, DM);
    tcast<<<dim3(2048), dim3(256), 0, stream>>>(W_out, wout, DM, EMB);
    concat_bias<<<dim3(4), dim3(256), 0, stream>>>(b_wr, b_qr, bcat);

    // WVQ = embb @ wcat^T + bcat   (M=32768, N=1024, K=1024), bf16 out
    gemm256<true><<<dim3(512), dim3(512), 0, stream>>>(
        embb, EMB, wcat, EMB, bcat, (void*)wvq, 1024, EMB, 4);

    transpose_wv<<<dim3(64, 8, 8), dim3(256), 0, stream>>>(
        (const unsigned short*)wvq, (unsigned short*)wvt);

    attn_mfma<<<dim3(MROWS / 64), dim3(256), 0, stream>>>(wvq, wvt, rbuf);

    // out = rbuf @ wout^T + b_out  (M=32768, N=1024, K=512), f32 out
    gemm256<false><<<dim3(512), dim3(512), 0, stream>>>(
        rbuf, DM, wout, DM, b_out, (void*)out, EMB, DM, 4);
}

// Round 9
// 242.145 us; speedup vs baseline: 9.3469x; 1.0347x over previous
//
#include <hip/hip_runtime.h>
#include <hip/hip_bf16.h>
#include <math.h>

// HashMemory: B=8, S=4096, E=1024, Dm=512, M=64 slots.
// memory at step t == write_vals of tokens [t-64, t-1]  => window-64 attention.
// Pipeline: WVQ = emb(f32, cast fused) @ [W_write|W_query] (256^2 MFMA GEMM);
// WVT = WV^T (tiled transpose); windowed attention (MFMA QK^T + wave-local
// softmax + MFMA PV); out = R @ W_out (256^2 MFMA GEMM, f32 out).
// r9: cast_bf16 kernel removed — GEMM1 reg-stages A from f32 and converts
// in-flight (T14 split: load early, ds_write after compute phases).

#define BATCH   8
#define S_LEN   4096
#define EMB     1024
#define DM      512
#define MROWS   (BATCH * S_LEN)          // 32768
#define SCALE_F 0.04419417382415922f     // 512^-0.5

typedef __attribute__((ext_vector_type(4))) float f32x4;
typedef __attribute__((ext_vector_type(8))) short short8;

__device__ __forceinline__ unsigned short f2bf(float f) {
    __hip_bfloat16 h = __float2bfloat16(f);
    return *reinterpret_cast<unsigned short*>(&h);
}

// ---------------------------------------------------------------------------
__global__ __launch_bounds__(256) void tcast(const float* __restrict__ in,
                                             __hip_bfloat16* __restrict__ out,
                                             int K, int N)
{
    int id = blockIdx.x * 256 + threadIdx.x;
    if (id >= K * N) return;
    int n = id / K, k = id % K;
    out[id] = __float2bfloat16(in[k * N + n]);
}

__global__ __launch_bounds__(256) void concat_bias(const float* __restrict__ a,
                                                   const float* __restrict__ b,
                                                   float* __restrict__ out)
{
    int i = blockIdx.x * 256 + threadIdx.x;
    if (i < 512) out[i] = a[i];
    else if (i < 1024) out[i] = b[i - 512];
}

// ---------------------------------------------------------------------------
// bf16 MFMA GEMM, 256x256 tile: C[M x N] = A[M x K] @ Bt[N x K]^T + bias.
// 512 threads = 8 waves (2x4); per-wave output 128x64; BK=64.
// LDS: [buf][A 32K | B 32K] x2 = 128KB. Rows 128B, chunk swizzle ^(row&7).
// AF32: A operand read as f32 and converted in-register during staging
// (fused cast); else A staged via global_load_lds like B.
// ---------------------------------------------------------------------------
template<bool BF16OUT, bool AF32>
__global__ __launch_bounds__(512, 2) void gemm256(
    const void* __restrict__ Av, int lda,
    const __hip_bfloat16* __restrict__ Bt, int ldb,
    const float* __restrict__ bias,
    void* __restrict__ Cv, int ldc,
    int K, int nbx)
{
    __shared__ __align__(16) char smem[131072];

    const int nwg = gridDim.x;
    const int bid = blockIdx.x;
    const int cpx = nwg >> 3;                    // nwg divisible by 8
    const int swz = (bid & 7) * cpx + (bid >> 3);
    const int bm0 = (swz / nbx) << 8;
    const int bn0 = (swz % nbx) << 8;

    const int tid  = threadIdx.x;
    const int lane = tid & 63;
    const int w    = tid >> 6;                   // 0..7
    const int wm   = w >> 2, wn = w & 3;         // 2x4 wave grid
    const int l15  = lane & 15, lhi = lane >> 4;
    const int nt   = K >> 6;

    // staging geometry: thread owns linear LDS slot tid*16 within each 8KB
    // pass-region => row r64 = tid>>3, phys chunk tid&7; swizzled global
    // source chunk = (tid&7) ^ (r64&7).
    const int r64 = tid >> 3;
    const int cg8 = ((tid & 7) ^ (r64 & 7)) << 3;    // source col (elems)

    const __hip_bfloat16* Ab = (const __hip_bfloat16*)Av;
    const float*          Af = (const float*)Av;

    // ---- staging helpers ----
    auto stageB = [&](int buf, int kt) {
#pragma unroll
        for (int hh = 0; hh < 2; ++hh)
#pragma unroll
            for (int i = 0; i < 2; ++i) {
                const __hip_bfloat16* g =
                    Bt + (size_t)(bn0 + hh * 128 + i * 64 + r64) * ldb + kt + cg8;
                char* l = smem + buf * 65536 + 32768 + hh * 16384 + i * 8192
                          + w * 1024;            // wave-uniform; HW adds lane*16
                __builtin_amdgcn_global_load_lds(
                    (const __attribute__((address_space(1))) unsigned int*)g,
                    (__attribute__((address_space(3))) unsigned int*)l, 16, 0, 0);
            }
    };
    auto stageA_lds = [&](int buf, int kt) {     // bf16 A via gload_lds
#pragma unroll
        for (int hh = 0; hh < 2; ++hh)
#pragma unroll
            for (int i = 0; i < 2; ++i) {
                const __hip_bfloat16* g =
                    Ab + (size_t)(bm0 + hh * 128 + i * 64 + r64) * lda + kt + cg8;
                char* l = smem + buf * 65536 + hh * 16384 + i * 8192 + w * 1024;
                __builtin_amdgcn_global_load_lds(
                    (const __attribute__((address_space(1))) unsigned int*)g,
                    (__attribute__((address_space(3))) unsigned int*)l, 16, 0, 0);
            }
    };

    float4 areg[4][2];                           // f32 A in flight (AF32)
    auto loadA = [&](int kt) {
#pragma unroll
        for (int p = 0; p < 4; ++p) {            // p = hh*2 + i
            const int hh = p >> 1, i = p & 1;
            const float* g = Af + (size_t)(bm0 + hh * 128 + i * 64 + r64) * lda
                             + kt + cg8;
            areg[p][0] = *(const float4*)g;
            areg[p][1] = *(const float4*)(g + 4);
        }
    };
    auto writeA = [&](int buf) {
#pragma unroll
        for (int p = 0; p < 4; ++p) {
            const int hh = p >> 1, i = p & 1;
            union { unsigned short s[8]; short8 v; } o;
            const float* f0 = (const float*)&areg[p][0];
            const float* f1 = (const float*)&areg[p][1];
#pragma unroll
            for (int k2 = 0; k2 < 4; ++k2) {
                o.s[k2]     = f2bf(f0[k2]);
                o.s[4 + k2] = f2bf(f1[k2]);
            }
            *(short8*)(smem + buf * 65536 + hh * 16384 + i * 8192 + tid * 16) = o.v;
        }
    };

    f32x4 acc[8][4] = {};

    // ---- prologue: tile 0 ----
    stageB(0, 0);
    if (AF32) { loadA(0); writeA(0); }
    else      { stageA_lds(0, 0); }
    __syncthreads();

    for (int t = 0; t < nt; ++t) {
        const int cur = t & 1;
        const bool pf = (t + 1 < nt);
        if (pf) {
            stageB(cur ^ 1, (t + 1) << 6);
            if (AF32) loadA((t + 1) << 6);       // f32 loads fly under MFMA
            else      stageA_lds(cur ^ 1, (t + 1) << 6);
        }

        const char* sA = smem + cur * 65536;
        const char* sB = sA + 32768;

#pragma unroll
        for (int q = 0; q < 4; ++q) {            // quadrant (mh, nh)
            const int mh = q >> 1, nh = q & 1;
            short8 af[4][2], bfv[2][2];
#pragma unroll
            for (int mi = 0; mi < 4; ++mi) {
                const int r = wm * 128 + mh * 64 + mi * 16 + l15;
#pragma unroll
                for (int kk = 0; kk < 2; ++kk) {
                    const int pc = (kk * 4 + lhi) ^ (r & 7);
                    af[mi][kk] = *(const short8*)(sA + r * 128 + (pc << 4));
                }
            }
#pragma unroll
            for (int ni = 0; ni < 2; ++ni) {
                const int r = wn * 64 + nh * 32 + ni * 16 + l15;
#pragma unroll
                for (int kk = 0; kk < 2; ++kk) {
                    const int pc = (kk * 4 + lhi) ^ (r & 7);
                    bfv[ni][kk] = *(const short8*)(sB + r * 128 + (pc << 4));
                }
            }
#pragma unroll
            for (int mi = 0; mi < 4; ++mi)
#pragma unroll
                for (int ni = 0; ni < 2; ++ni)
#pragma unroll
                    for (int kk = 0; kk < 2; ++kk)
                        acc[mh * 4 + mi][nh * 2 + ni] =
                            __builtin_amdgcn_mfma_f32_16x16x32_bf16(
                                af[mi][kk], bfv[ni][kk],
                                acc[mh * 4 + mi][nh * 2 + ni], 0, 0, 0);
        }

        if (AF32 && pf) writeA(cur ^ 1);   // cvt+ds_write after compute (T14)
        __syncthreads();                   // drains stages; buffers swap
    }

    // ---- epilogue ----
    float bv[4];
#pragma unroll
    for (int N = 0; N < 4; ++N)
        bv[N] = bias[bn0 + wn * 64 + (N >> 1) * 32 + (N & 1) * 16 + l15];

#pragma unroll
    for (int M = 0; M < 8; ++M)
#pragma unroll
        for (int N = 0; N < 4; ++N)
#pragma unroll
            for (int reg = 0; reg < 4; ++reg) {
                int row = bm0 + wm * 128 + (M >> 2) * 64 + (M & 3) * 16
                          + lhi * 4 + reg;
                int col = bn0 + wn * 64 + (N >> 1) * 32 + (N & 1) * 16 + l15;
                float v = acc[M][N][reg] + bv[N];
                if (BF16OUT)
                    ((__hip_bfloat16*)Cv)[(size_t)row * ldc + col] = __float2bfloat16(v);
                else
                    ((float*)Cv)[(size_t)row * ldc + col] = v;
            }
}

// ---------------------------------------------------------------------------
// WV transpose: wvq[b][t][0:512] (stride 1024) -> wvt[b][d][t]
// ---------------------------------------------------------------------------
__global__ __launch_bounds__(256) void transpose_wv(
    const unsigned short* __restrict__ wvq,
    unsigned short* __restrict__ wvt)
{
    __shared__ unsigned short tl[64][66];
    const int tx  = blockIdx.x;
    const int dx  = blockIdx.y;
    const int b   = blockIdx.z;
    const int tid = threadIdx.x;
    const int r   = tid >> 3;
    const int c8  = (tid & 7) * 8;
    const size_t bbase = (size_t)b << 12;

#pragma unroll
    for (int it = 0; it < 2; ++it) {
        int row = r + it * 32;
        uint4 v = *(const uint4*)(wvq + ((bbase + tx * 64 + row) << 10) + dx * 64 + c8);
        *(unsigned*)&tl[row][c8 + 0] = v.x;
        *(unsigned*)&tl[row][c8 + 2] = v.y;
        *(unsigned*)&tl[row][c8 + 4] = v.z;
        *(unsigned*)&tl[row][c8 + 6] = v.w;
    }
    __syncthreads();
#pragma unroll
    for (int it = 0; it < 2; ++it) {
        int drow = r + it * 32;
        union { unsigned short s[8]; uint4 v; } o;
#pragma unroll
        for (int k = 0; k < 8; ++k) o.s[k] = tl[c8 + k][drow];
        *(uint4*)(wvt + (((size_t)b * 512 + dx * 64 + drow) << 12) + tx * 64 + c8) = o.v;
    }
}

// ---------------------------------------------------------------------------
// MFMA windowed attention. Block = 64 tokens, 4 waves.
// ---------------------------------------------------------------------------
__global__ __launch_bounds__(256) void attn_mfma(
    const __hip_bfloat16* __restrict__ WVQ,   // [32768][1024]: 0:512=WV, 512:=Q
    const __hip_bfloat16* __restrict__ WVT,   // [8][512][4096]
    __hip_bfloat16* __restrict__ R)           // [32768][512]
{
    __shared__ __align__(16) unsigned short p_lds[64][136];  // 17408 B

    const int blk = blockIdx.x;
    const int b   = blk >> 6;
    const int t0  = (blk & 63) << 6;
    const int jmin = (t0 == 0) ? 64 : 0;
    const size_t bbase = (size_t)b << 12;
    const int tid  = threadIdx.x;
    const int lane = tid & 63;
    const int w    = tid >> 6;
    const int l15  = lane & 15;
    const int lhi  = lane >> 4;

    // ---- QK^T:  S[64][128] ----
    f32x4 acc[8] = {};
    const __hip_bfloat16* q0 =
        WVQ + ((bbase + t0 + w * 16 + l15) << 10) + 512 + lhi * 8;

    const __hip_bfloat16* brow[8];
#pragma unroll
    for (int nt = 0; nt < 8; ++nt) {
        int aj = t0 - 64 + nt * 16 + l15;
        if (aj < 0) aj = 0;                 // clamped; masked below
        brow[nt] = WVQ + ((bbase + aj) << 10) + lhi * 8;
    }

    for (int kt = 0; kt < 16; ++kt) {
        short8 qa = *(const short8*)(q0 + kt * 32);
#pragma unroll
        for (int nt = 0; nt < 8; ++nt) {
            short8 bv = *(const short8*)(brow[nt] + kt * 32);
            acc[nt] = __builtin_amdgcn_mfma_f32_16x16x32_bf16(qa, bv, acc[nt], 0, 0, 0);
        }
    }

    // ---- wave-local softmax ----
    float m4[4] = { -1e30f, -1e30f, -1e30f, -1e30f };
#pragma unroll
    for (int nt = 0; nt < 8; ++nt)
#pragma unroll
        for (int reg = 0; reg < 4; ++reg) {
            int i = w * 16 + lhi * 4 + reg;
            int j = nt * 16 + l15;
            bool valid = (j >= i) && (j <= i + 63) && (j >= jmin);
            float s = valid ? acc[nt][reg] * SCALE_F : -1e30f;
            acc[nt][reg] = s;
            m4[reg] = fmaxf(m4[reg], s);
        }
#pragma unroll
    for (int off = 8; off >= 1; off >>= 1)
#pragma unroll
        for (int reg = 0; reg < 4; ++reg)
            m4[reg] = fmaxf(m4[reg], __shfl_xor(m4[reg], off, 64));

    float sum4[4] = {};
#pragma unroll
    for (int nt = 0; nt < 8; ++nt)
#pragma unroll
        for (int reg = 0; reg < 4; ++reg) {
            float s = acc[nt][reg];
            float p = (s > -1e29f) ? __expf(s - m4[reg]) : 0.f;
            acc[nt][reg] = p;
            sum4[reg] += p;
        }
#pragma unroll
    for (int off = 8; off >= 1; off >>= 1)
#pragma unroll
        for (int reg = 0; reg < 4; ++reg)
            sum4[reg] += __shfl_xor(sum4[reg], off, 64);

    float rs4[4];
#pragma unroll
    for (int reg = 0; reg < 4; ++reg)
        rs4[reg] = (sum4[reg] > 0.f) ? 1.f / sum4[reg] : 0.f;

#pragma unroll
    for (int nt = 0; nt < 8; ++nt)
#pragma unroll
        for (int reg = 0; reg < 4; ++reg)
            p_lds[w * 16 + lhi * 4 + reg][nt * 16 + l15] =
                f2bf(acc[nt][reg] * rs4[reg]);

    __syncthreads();

    // ---- PV ----
    short8 pa[4];
#pragma unroll
    for (int kt = 0; kt < 4; ++kt)
        pa[kt] = *(const short8*)&p_lds[w * 16 + l15][kt * 32 + lhi * 8];

    int tclamp[4];
#pragma unroll
    for (int kt = 0; kt < 4; ++kt) {
        int ti = t0 - 64 + kt * 32 + lhi * 8;
        tclamp[kt] = ti < 0 ? 0 : ti;       // 8-chunks never straddle 0
    }

    const size_t vbase = (size_t)b * 512;
    for (int nt = 0; nt < 32; ++nt) {
        int d = nt * 16 + l15;
        f32x4 a = {};
#pragma unroll
        for (int kt = 0; kt < 4; ++kt) {
            short8 bv = *(const short8*)(WVT + ((vbase + d) << 12) + tclamp[kt]);
            a = __builtin_amdgcn_mfma_f32_16x16x32_bf16(pa[kt], bv, a, 0, 0, 0);
        }
        size_t rb = (bbase + t0 + w * 16 + lhi * 4) << 9;
#pragma unroll
        for (int reg = 0; reg < 4; ++reg)
            R[rb + ((size_t)reg << 9) + d] = __float2bfloat16(a[reg]);
    }
}

// ---------------------------------------------------------------------------
extern "C" void kernel_launch(void* const* d_in, const int* in_sizes, int n_in,
                              void* d_out, int out_size, void* d_ws, size_t ws_size,
                              hipStream_t stream)
{
    const float* emb   = (const float*)d_in[0];
    const float* W_wr  = (const float*)d_in[1];
    const float* b_wr  = (const float*)d_in[2];
    const float* W_qr  = (const float*)d_in[3];
    const float* b_qr  = (const float*)d_in[4];
    const float* W_out = (const float*)d_in[5];
    const float* b_out = (const float*)d_in[6];
    float* out = (float*)d_out;

    char* ws = (char*)d_ws;
    __hip_bfloat16* wvt  = (__hip_bfloat16*)(ws);                         // 32MB
    __hip_bfloat16* wvq  = (__hip_bfloat16*)(ws + (((size_t)64) << 20));  // 64MB
    __hip_bfloat16* rbuf = (__hip_bfloat16*)(ws + (((size_t)128) << 20)); // 32MB
    __hip_bfloat16* wcat = (__hip_bfloat16*)(ws + (((size_t)160) << 20)); // 2MB
    __hip_bfloat16* wout = (__hip_bfloat16*)(ws + (((size_t)162) << 20)); // 1MB
    float*          bcat = (float*)        (ws + (((size_t)163) << 20));  // 4KB

    tcast<<<dim3(2048), dim3(256), 0, stream>>>(W_wr, wcat, EMB, DM);
    tcast<<<dim3(2048), dim3(256), 0, stream>>>(W_qr, wcat + (size_t)DM * EMB, EMB, DM);
    tcast<<<dim3(2048), dim3(256), 0, stream>>>(W_out, wout, DM, EMB);
    concat_bias<<<dim3(4), dim3(256), 0, stream>>>(b_wr, b_qr, bcat);

    // WVQ = emb(f32) @ wcat^T + bcat   (M=32768, N=1024, K=1024), bf16 out
    gemm256<true, true><<<dim3(512), dim3(512), 0, stream>>>(
        (const void*)emb, EMB, wcat, EMB, bcat, (void*)wvq, 1024, EMB, 4);

    transpose_wv<<<dim3(64, 8, 8), dim3(256), 0, stream>>>(
        (const unsigned short*)wvq, (unsigned short*)wvt);

    attn_mfma<<<dim3(MROWS / 64), dim3(256), 0, stream>>>(wvq, wvt, rbuf);

    // out = rbuf @ wout^T + b_out  (M=32768, N=1024, K=512), f32 out
    gemm256<false, false><<<dim3(512), dim3(512), 0, stream>>>(
        (const void*)rbuf, DM, wout, DM, b_out, (void*)out, EMB, DM, 4);
}